// Round 17
// baseline (1401.062 us; speedup 1.0000x reference)
//
#include <hip/hip_runtime.h>
#include <math.h>

#define OPI 64
#define RPI 1024
#define N_OBJ 512       // B*OPI
#define R_REL 8192      // B*RPI
#define OBJ_DIM 4096
#define H 512
#define NOC 151
#define NRC 51
#define T_ITERS 3
#define IOU_THRESH 0.3f

typedef unsigned short u16;
typedef unsigned int u32;
typedef unsigned long long u64;
typedef __attribute__((ext_vector_type(4))) float f32x4;
typedef __attribute__((ext_vector_type(8))) short bf16x8;
typedef __attribute__((ext_vector_type(2))) unsigned int u32x2;
typedef __attribute__((ext_vector_type(8))) short s16x8;

enum { EPI_STORE = 0, EPI_BIAS = 1, EPI_GATE = 3, EPI_NEWH = 4 };

__device__ inline u16 f2bf(float x) {
  u32 u = __float_as_uint(x);
  u32 r = (u + 0x7fffu + ((u >> 16) & 1u)) >> 16;
  return (u16)r;
}
__device__ inline float bf2f(u16 h) { return __uint_as_float(((u32)h) << 16); }
// HW packed fp32->bf16 (RTNE, matches f2bf): lo half = cvt(a), hi half = cvt(b)
__device__ inline u32 cvtpk(float a, float b) {
  u32 r;
  asm("v_cvt_pk_bf16_f32 %0, %1, %2" : "=v"(r) : "v"(a), "v"(b));
  return r;
}

// ---------------------------------------------------------------------------
// Merged weight prep (10 transpose/split jobs) + input softmax, ONE dispatch.
// ---------------------------------------------------------------------------
struct PJob {
  const float* W1; const float* W2; u16* oh; u16* ol;
  int ld1, K1, ld2, K2, coloff, ncols, N, Kpad, blk0, nkb;
};
struct PJobs { PJob j[10]; const float* smx_in; float* smx_out; int smx_blk0; };

__global__ __launch_bounds__(256) void prep_all(PJobs jobs) {
  __shared__ float tile[64][65];
  __shared__ float red[4];
  const int bid = blockIdx.x;
  const int t = threadIdx.x;

  if (bid >= jobs.smx_blk0) {           // ---- softmax rows
    int row = bid - jobs.smx_blk0;
    const float* X = jobs.smx_in;
    float* P = jobs.smx_out;
    float x = (t < NOC) ? X[row * NOC + t] : -3.4e38f;
    float m = x;
#pragma unroll
    for (int o = 32; o > 0; o >>= 1) m = fmaxf(m, __shfl_xor(m, o, 64));
    if ((t & 63) == 0) red[t >> 6] = m;
    __syncthreads();
    float mm = fmaxf(fmaxf(red[0], red[1]), fmaxf(red[2], red[3]));
    float e = (t < NOC) ? expf(x - mm) : 0.f;
    float s = e;
#pragma unroll
    for (int o = 32; o > 0; o >>= 1) s += __shfl_xor(s, o, 64);
    __syncthreads();
    if ((t & 63) == 0) red[t >> 6] = s;
    __syncthreads();
    float ss = red[0] + red[1] + red[2] + red[3];
    if (t < NOC) P[row * NOC + t] = e / ss;
    return;
  }

  int ji = 0;
#pragma unroll
  for (int i = 1; i < 10; ++i) if (bid >= jobs.j[i].blk0) ji = i;
  const PJob J = jobs.j[ji];
  const int local = bid - J.blk0;
  const int k0 = (local % J.nkb) * 64;
  const int n0 = (local / J.nkb) * 64;
  const int lane = t & 63;
  const int w = t >> 6;
#pragma unroll
  for (int p = 0; p < 16; ++p) {
    int kl = w * 16 + p;
    int k = k0 + kl;
    int n = n0 + lane;
    float v = 0.f;
    if (n < J.ncols) {
      if (k < J.K1) v = J.W1[(size_t)k * J.ld1 + J.coloff + n];
      else if (k - J.K1 < J.K2) v = J.W2[(size_t)(k - J.K1) * J.ld2 + J.coloff + n];
    }
    tile[kl][lane] = v;
  }
  __syncthreads();
#pragma unroll
  for (int p = 0; p < 16; ++p) {
    int nl = w * 16 + p;
    int n = n0 + nl;
    int k = k0 + lane;
    if (n < J.N && k < J.Kpad) {
      float v = tile[lane][nl];
      u16 h = f2bf(v);
      J.oh[(size_t)n * J.Kpad + k] = h;
      J.ol[(size_t)n * J.Kpad + k] = f2bf(v - bf2f(h));
    }
  }
}

// ---------------------------------------------------------------------------
// Split-bf16 MFMA GEMM (R16 core; only the block swizzle changed).
// For rel-side grids (nby%8==0): A-band-affinity swizzle — all nbx blocks of
// one output row-band land on ONE XCD so its private L2 serves the A-refetch
// (A-refetch latency was the measured bottleneck on newh/gates/proj).
// Small obj-side grids keep the bijective round-robin swizzle.
// ---------------------------------------------------------------------------
template<int EPI, bool DUAL, bool GATHER, bool PAIR, bool SPLIT>
__global__ __launch_bounds__(256, 2) void mgemm_k(
    int M, int N, int K1, int K2, int nkt,
    const float* __restrict__ A1, int lda1,
    const float* __restrict__ A2, int lda2,
    const u16* __restrict__ Bth, const u16* __restrict__ Btl,
    const u16* __restrict__ Bth2, const u16* __restrict__ Btl2,
    const float* __restrict__ bias,
    float* __restrict__ C, int ldc, float* __restrict__ C2,
    const int* __restrict__ ridx,
    const float* __restrict__ Hb, int ldh,
    const float* __restrict__ Zin,
    float* __restrict__ Zout, float* __restrict__ RHout,
    float* __restrict__ part, int ktchunk)
{
  __shared__ u16 lAh[2][128 * 32];
  __shared__ u16 lAl[2][128 * 32];
  __shared__ u16 lBh[2][128 * 32];
  __shared__ u16 lBl[2][128 * 32];
  const int t = threadIdx.x;
  const int lane = t & 63;
  const int wid = t >> 6;          // 0..3
  const int wm = wid >> 1;         // 0..1 (64-row half)
  const int wn = wid & 1;          // 0..1 (64-col half)

  // ---- block swizzle
  const int nbx = gridDim.x, nby = gridDim.y;
  const int nwg = nbx * nby;
  int lin = blockIdx.y * nbx + blockIdx.x;
  int bx, by;
  if ((nby & 7) == 0) {
    // A-band-affinity: same by -> same XCD (hw round-robin = lin % 8)
    int xcd = lin & 7;
    int q = lin >> 3;
    int qn = q / nbx;
    by = xcd * (nby >> 3) + qn;
    bx = q - qn * nbx;
  } else {
    int lid = (lin & 7) * (nwg >> 3) + (lin >> 3);
    bx = lid % nbx;
    by = lid / nbx;
  }

  const int m0 = by * 128;
  const int n0 = bx * 128;
  const int Kpad = nkt * 32;

  const float* A1p = A1; int ldap = lda1;
  const u16* Bhp = Bth; const u16* Blp = Btl;
  float* Cp = C;
  bool gath = GATHER;
  if (PAIR && blockIdx.z == 1) {
    A1p = A2; ldap = lda2; Bhp = Bth2; Blp = Btl2; Cp = C2; gath = false;
  }

  f32x4 acc[4][4];
#pragma unroll
  for (int m = 0; m < 4; ++m)
#pragma unroll
    for (int n = 0; n < 4; ++n) acc[m][n] = f32x4{0.f, 0.f, 0.f, 0.f};

  const int a_row = t >> 3;        // 0..31 (+i*32)
  const int a_kq  = t & 7;
  int g_si[4], g_oi[4];
  if (gath) {
#pragma unroll
    for (int i = 0; i < 4; ++i) {
      int gm = m0 + a_row + i * 32;
      g_si[i] = ridx[gm * 3 + 1];
      g_oi[i] = ridx[gm * 3 + 2];
    }
  }
  const int b_row  = t >> 2;       // 0..63 (+i*64)
  const int b_slot = t & 3;

  int ktb = 0, kte = nkt;
  if (SPLIT) {
    ktb = blockIdx.z * ktchunk;
    kte = min(nkt, ktb + ktchunk);
  }

  float4 rA[4];
  s16x8 rBh[2], rBl[2];

  auto loadA = [&](int kt) {
    const int gk = kt * 32 + a_kq * 4;
#pragma unroll
    for (int i = 0; i < 4; ++i) {
      const int gm = m0 + a_row + i * 32;
      if (gath) {
        float4 va = *(const float4*)&A1p[(size_t)g_si[i] * ldap + gk];
        float4 vb = *(const float4*)&A1p[(size_t)g_oi[i] * ldap + gk];
        rA[i] = make_float4(va.x + vb.x, va.y + vb.y, va.z + vb.z, va.w + vb.w);
      } else if (!DUAL) {
        rA[i] = *(const float4*)&A1p[(size_t)gm * ldap + gk];
      } else {
        if (gk + 3 < K1) {
          rA[i] = *(const float4*)&A1p[(size_t)gm * lda1 + gk];
        } else if (gk >= K1 && gk + 3 < K1 + K2 && (lda2 & 3) == 0) {
          rA[i] = *(const float4*)&A2[(size_t)gm * lda2 + (gk - K1)];
        } else {
          float xs[4];
#pragma unroll
          for (int e = 0; e < 4; ++e) {
            int gke = gk + e;
            float xv = 0.f;
            if (gke < K1) xv = A1p[(size_t)gm * lda1 + gke];
            else if (gke < K1 + K2) xv = A2[(size_t)gm * lda2 + (gke - K1)];
            xs[e] = xv;
          }
          rA[i] = make_float4(xs[0], xs[1], xs[2], xs[3]);
        }
      }
    }
  };
  auto loadB = [&](int kt) {
#pragma unroll
    for (int i = 0; i < 2; ++i) {
      const size_t goff = (size_t)(n0 + b_row + i * 64) * Kpad + kt * 32 + b_slot * 8;
      rBh[i] = *(const s16x8*)&Bhp[goff];
      rBl[i] = *(const s16x8*)&Blp[goff];
    }
  };
  auto stage = [&](int buf) {
#pragma unroll
    for (int i = 0; i < 4; ++i) {
      const int row = a_row + i * 32;
      float x0 = rA[i].x, x1 = rA[i].y, x2 = rA[i].z, x3 = rA[i].w;
      u32 h01 = cvtpk(x0, x1);
      u32 h23 = cvtpk(x2, x3);
      float r0 = __uint_as_float(h01 << 16);
      float r1 = __uint_as_float(h01 & 0xffff0000u);
      float r2 = __uint_as_float(h23 << 16);
      float r3 = __uint_as_float(h23 & 0xffff0000u);
      u32 l01 = cvtpk(x0 - r0, x1 - r1);
      u32 l23 = cvtpk(x2 - r2, x3 - r3);
      const int base = row * 32 + (((a_kq >> 1) ^ ((row >> 1) & 3)) << 3) + (a_kq & 1) * 4;
      *reinterpret_cast<u32x2*>(&lAh[buf][base]) = u32x2{h01, h23};
      *reinterpret_cast<u32x2*>(&lAl[buf][base]) = u32x2{l01, l23};
    }
#pragma unroll
    for (int i = 0; i < 2; ++i) {
      const int row = b_row + i * 64;
      const int base = row * 32 + ((b_slot ^ ((row >> 1) & 3)) << 3);
      *reinterpret_cast<s16x8*>(&lBh[buf][base]) = rBh[i];
      *reinterpret_cast<s16x8*>(&lBl[buf][base]) = rBl[i];
    }
  };

  const int fr = lane & 15;
  const int kg = lane >> 4;

  if (ktb < kte) {
    loadA(ktb);
    loadB(ktb);
    stage(0);
    __syncthreads();
    const int nk = kte - ktb;
    for (int kk = 0; kk < nk; ++kk) {
      const int cur = kk & 1;
      const bool more = (kk + 1 < nk);
      if (more) { loadA(ktb + kk + 1); loadB(ktb + kk + 1); }  // fly under MFMAs
      bf16x8 ah[4], al[4], bh[4], bl[4];
#pragma unroll
      for (int m = 0; m < 4; ++m) {
        const int r = wm * 64 + m * 16 + fr;
        const int addr = r * 32 + ((kg ^ ((r >> 1) & 3)) << 3);
        ah[m] = *reinterpret_cast<const bf16x8*>(&lAh[cur][addr]);
        al[m] = *reinterpret_cast<const bf16x8*>(&lAl[cur][addr]);
      }
#pragma unroll
      for (int n = 0; n < 4; ++n) {
        const int r = wn * 64 + n * 16 + fr;
        const int addr = r * 32 + ((kg ^ ((r >> 1) & 3)) << 3);
        bh[n] = *reinterpret_cast<const bf16x8*>(&lBh[cur][addr]);
        bl[n] = *reinterpret_cast<const bf16x8*>(&lBl[cur][addr]);
      }
      __builtin_amdgcn_s_setprio(1);
#pragma unroll
      for (int m = 0; m < 4; ++m)
#pragma unroll
        for (int n = 0; n < 4; ++n) {
          acc[m][n] = __builtin_amdgcn_mfma_f32_16x16x32_bf16(ah[m], bh[n], acc[m][n], 0, 0, 0);
          acc[m][n] = __builtin_amdgcn_mfma_f32_16x16x32_bf16(ah[m], bl[n], acc[m][n], 0, 0, 0);
          acc[m][n] = __builtin_amdgcn_mfma_f32_16x16x32_bf16(al[m], bh[n], acc[m][n], 0, 0, 0);
        }
      __builtin_amdgcn_s_setprio(0);
      if (more) stage(cur ^ 1);
      __syncthreads();
    }
  }

  // ---- epilogue (C/D layout: col = lane&15, row = (lane>>4)*4 + j)
  const int col = lane & 15;
  const int rb = (lane >> 4) * 4;
  if (SPLIT) {
    const int Npad = gridDim.x * 128;
    float* pp = part + (size_t)blockIdx.z * M * Npad;
#pragma unroll
    for (int m = 0; m < 4; ++m)
#pragma unroll
      for (int n = 0; n < 4; ++n) {
        const int gn = n0 + wn * 64 + n * 16 + col;
#pragma unroll
        for (int j = 0; j < 4; ++j) {
          const int gm = m0 + wm * 64 + m * 16 + rb + j;
          pp[(size_t)gm * Npad + gn] = acc[m][n][j];
        }
      }
    return;
  }
#pragma unroll
  for (int m = 0; m < 4; ++m) {
#pragma unroll
    for (int n = 0; n < 4; ++n) {
      const int gn = n0 + wn * 64 + n * 16 + col;
      if (gn >= N) continue;
#pragma unroll
      for (int j = 0; j < 4; ++j) {
        const int gm = m0 + wm * 64 + m * 16 + rb + j;
        float v = acc[m][n][j];
        if (EPI == EPI_STORE) {
          Cp[(size_t)gm * ldc + gn] = v;
        } else if (EPI == EPI_BIAS) {
          Cp[(size_t)gm * ldc + gn] = v + bias[gn];
        } else if (EPI == EPI_GATE) {
          float g = 1.f / (1.f + expf(-(v + bias[gn])));
          int half = N >> 1;
          if (gn < half) Zout[(size_t)gm * half + gn] = g;
          else RHout[(size_t)gm * half + (gn - half)] = g * Hb[(size_t)gm * ldh + (gn - half)];
        } else if (EPI == EPI_NEWH) {
          float nv = tanhf(v + bias[gn]);
          float z = Zin[(size_t)gm * N + gn];
          float h = Hb[(size_t)gm * ldh + gn];
          Cp[(size_t)gm * ldc + gn] = (1.f - z) * h + z * nv;
        }
      }
    }
  }
}

// ---------------------------------------------------------------------------
// Split-K reduce + epilogue (single and dual-job).
// ---------------------------------------------------------------------------
template<int EPI>
__device__ inline void reduce_body(int blk, int S, int M, int N, int Npad,
    const float* __restrict__ part, const float* __restrict__ bias,
    float* __restrict__ C, int ldc,
    const float* __restrict__ Hb, int ldh,
    const float* __restrict__ Zin,
    float* __restrict__ Zout, float* __restrict__ RHout)
{
  int idx = blk * 256 + (int)threadIdx.x;
  if (idx >= M * Npad) return;
  int m = idx / Npad;
  int n = idx - m * Npad;
  if (n >= N) return;
  size_t stride = (size_t)M * Npad;
  float v = 0.f;
  for (int s = 0; s < S; ++s) v += part[s * stride + idx];
  if (EPI == EPI_BIAS) {
    C[(size_t)m * ldc + n] = v + bias[n];
  } else if (EPI == EPI_GATE) {
    float g = 1.f / (1.f + expf(-(v + bias[n])));
    int half = N >> 1;
    if (n < half) Zout[(size_t)m * half + n] = g;
    else RHout[(size_t)m * half + (n - half)] = g * Hb[(size_t)m * ldh + (n - half)];
  } else if (EPI == EPI_NEWH) {
    float nv = tanhf(v + bias[n]);
    float z = Zin[(size_t)m * N + n];
    float h = Hb[(size_t)m * ldh + n];
    C[(size_t)m * ldc + n] = (1.f - z) * h + z * nv;
  }
}

template<int EPI>
__global__ __launch_bounds__(256) void epi_reduce(
    int S, int M, int N, int Npad,
    const float* __restrict__ part, const float* __restrict__ bias,
    float* __restrict__ C, int ldc,
    const float* __restrict__ Hb, int ldh,
    const float* __restrict__ Zin,
    float* __restrict__ Zout, float* __restrict__ RHout)
{
  reduce_body<EPI>(blockIdx.x, S, M, N, Npad, part, bias, C, ldc, Hb, ldh, Zin, Zout, RHout);
}

template<int E1, int E2>
__global__ __launch_bounds__(256) void epi_reduce2x(
    int nblk1,
    int S1, int M1, int N1, int P1, const float* p1, const float* b1, float* C1, int l1,
    const float* Hb1, const float* Z1, float* Zo1, float* Rh1,
    int S2, int M2, int N2, int P2, const float* p2, const float* b2, float* C2, int l2,
    const float* Hb2, const float* Z2, float* Zo2, float* Rh2)
{
  if ((int)blockIdx.x < nblk1)
    reduce_body<E1>(blockIdx.x, S1, M1, N1, P1, p1, b1, C1, l1, Hb1, H, Z1, Zo1, Rh1);
  else
    reduce_body<E2>(blockIdx.x - nblk1, S2, M2, N2, P2, p2, b2, C2, l2, Hb2, H, Z2, Zo2, Rh2);
}

// row softmax over NOC=151 columns, one block per row
__global__ __launch_bounds__(256) void softmax_k(const float* __restrict__ X,
                                                 float* __restrict__ P)
{
  int row = blockIdx.x;
  int t = threadIdx.x;
  __shared__ float red[4];
  float x = (t < NOC) ? X[row * NOC + t] : -3.4e38f;
  float m = x;
#pragma unroll
  for (int o = 32; o > 0; o >>= 1) m = fmaxf(m, __shfl_xor(m, o, 64));
  if ((t & 63) == 0) red[t >> 6] = m;
  __syncthreads();
  float mm = fmaxf(fmaxf(red[0], red[1]), fmaxf(red[2], red[3]));
  float e = (t < NOC) ? expf(x - mm) : 0.f;
  float s = e;
#pragma unroll
  for (int o = 32; o > 0; o >>= 1) s += __shfl_xor(s, o, 64);
  __syncthreads();
  if ((t & 63) == 0) red[t >> 6] = s;
  __syncthreads();
  float ss = red[0] + red[1] + red[2] + red[3];
  if (t < NOC) P[row * NOC + t] = e / ss;
}

// deterministic scatter-free m_obj
__global__ __launch_bounds__(256) void m_obj_gather_k(const float* __restrict__ hm,
                                                      const int* __restrict__ ridx,
                                                      float* __restrict__ m_obj)
{
  int n = blockIdx.x;
  int im = n >> 6;
  int col = threadIdx.x;
  float acc0 = 0.f, acc1 = 0.f;
  int r0 = im * RPI, r1 = r0 + RPI;
  for (int r = r0; r < r1; ++r) {
    int s = ridx[r * 3 + 1];
    int o = ridx[r * 3 + 2];
    int cnt = (s == n) + (o == n);
    if (cnt) {
      float f = (float)cnt;
      acc0 = fmaf(f, hm[r * H + col], acc0);
      acc1 = fmaf(f, hm[r * H + col + 256], acc1);
    }
  }
  m_obj[n * H + col] = acc0;
  m_obj[n * H + col + 256] = acc1;
}

// ---------------------------------------------------------------------------
// Per-class NMS: stable bitonic sort + bitmask suppression.
// ---------------------------------------------------------------------------
__global__ __launch_bounds__(512) void nms_k(const float* __restrict__ probs2,
                                             const float* __restrict__ boxes,
                                             float* __restrict__ keepmask)
{
  int c = blockIdx.x + 1;
  int t = threadIdx.x;
  __shared__ float sc[512];
  __shared__ int   si[512];
  __shared__ float bx0[512], by0[512], bx1[512], by1[512], sar[512];
  __shared__ u64   msk[512][8];
  __shared__ u64   keepw_s[8];

  sc[t] = probs2[t * NOC + c];
  si[t] = t;
  __syncthreads();

  for (int k = 2; k <= 512; k <<= 1) {
    for (int j = k >> 1; j > 0; j >>= 1) {
      int p = t ^ j;
      if (p > t) {
        float s1 = sc[t], s2 = sc[p];
        int   i1 = si[t], i2 = si[p];
        bool tBefore = (s1 > s2) || (s1 == s2 && i1 < i2);
        bool up = ((t & k) == 0);
        if (up != tBefore) { sc[t] = s2; sc[p] = s1; si[t] = i2; si[p] = i1; }
      }
      __syncthreads();
    }
  }

  {
    const float* b = &boxes[(si[t] * NOC + c) * 4];
    float x0 = b[0], y0 = b[1], x1 = b[2], y1 = b[3];
    bx0[t] = x0; by0[t] = y0; bx1[t] = x1; by1[t] = y1;
    sar[t] = (x1 - x0) * (y1 - y0);
  }
  __syncthreads();

  {
    const float x0 = bx0[t], y0 = by0[t], x1 = bx1[t], y1 = by1[t], ar = sar[t];
#pragma unroll
    for (int w = 0; w < 8; ++w) {
      u64 bits = 0ull;
#pragma unroll 4
      for (int b = 0; b < 64; ++b) {
        const int j = w * 64 + b;
        float lx = fmaxf(x0, bx0[j]);
        float ly = fmaxf(y0, by0[j]);
        float rx = fminf(x1, bx1[j]);
        float ry = fminf(y1, by1[j]);
        float ww = fmaxf(rx - lx, 0.f);
        float hh = fmaxf(ry - ly, 0.f);
        float inter = ww * hh;
        float iou = inter / (ar + sar[j] - inter + 1e-9f);
        bits |= ((u64)((j > t) && (iou > IOU_THRESH))) << b;
      }
      msk[t][w] = bits;
    }
  }
  __syncthreads();

  if (t < 64) {
    const int w = t & 7;
    u64 keepw = ~0ull;
    u64 m = msk[0][w];
    for (int i = 0; i < 512; ++i) {
      u64 mn = (i + 1 < 512) ? msk[i + 1][w] : 0ull;
      u64 kw = __shfl(keepw, i >> 6, 64);
      if ((kw >> (i & 63)) & 1ull) keepw &= ~m;
      m = mn;
    }
    if (t < 8) keepw_s[t] = keepw;
  }
  __syncthreads();

  const u64 kw = keepw_s[t >> 6];
  keepmask[(c - 1) * N_OBJ + si[t]] = ((kw >> (t & 63)) & 1ull) ? 1.f : 0.f;
}

__global__ void pred_k(const float* __restrict__ probs2,
                       const float* __restrict__ keepmask,
                       float* __restrict__ out)
{
  int i = threadIdx.x + blockIdx.x * 256;
  if (i >= N_OBJ) return;
  float best = -1.f;
  int bc = 0;
  for (int c = 0; c < NOC - 1; ++c) {
    float v = keepmask[c * N_OBJ + i] * probs2[i * NOC + c + 1];
    if (v > best) { best = v; bc = c; }
  }
  out[i] = (float)(bc + 1);
}

extern "C" void kernel_launch(void* const* d_in, const int* in_sizes, int n_in,
                              void* d_out, int out_size, void* d_ws, size_t ws_size,
                              hipStream_t stream) {
  const float* obj_fmaps  = (const float*)d_in[1];
  const float* obj_logits = (const float*)d_in[2];
  const int*   rel_inds   = (const int*)d_in[3];
  const float* vr         = (const float*)d_in[4];
  const float* boxes      = (const float*)d_in[5];
  const float* W_obj_proj = (const float*)d_in[6];
  const float* b_obj_proj = (const float*)d_in[7];
  const float* W_rel_proj = (const float*)d_in[8];
  const float* b_rel_proj = (const float*)d_in[9];
  const float* W_emb      = (const float*)d_in[10];
  const float* W_msg_rel  = (const float*)d_in[11];
  const float* W_msg_obj  = (const float*)d_in[12];
  const float* W_gru_obj  = (const float*)d_in[13];
  const float* U_gru_obj  = (const float*)d_in[14];
  const float* b_gru_obj  = (const float*)d_in[15];
  const float* W_gru_rel  = (const float*)d_in[16];
  const float* U_gru_rel  = (const float*)d_in[17];
  const float* b_gru_rel  = (const float*)d_in[18];
  const float* W_cls_rel  = (const float*)d_in[19];
  const float* b_cls_rel  = (const float*)d_in[20];
  const float* W_cls_obj  = (const float*)d_in[21];
  const float* b_cls_obj  = (const float*)d_in[22];

  float* ws = (float*)d_ws;
  const size_t RH = (size_t)R_REL * H;     // 4,194,304
  const size_t NH = (size_t)N_OBJ * H;
  float* h_rel  = ws;
  float* m_rel  = h_rel  + RH;
  float* z_rel  = m_rel  + RH;   // aliased with hm
  float* rh_rel = z_rel  + RH;
  float* h_obj  = rh_rel + RH;
  float* m_obj  = h_obj  + NH;
  float* z_obj  = m_obj  + NH;
  float* rh_obj = z_obj  + NH;
  float* obj_probs  = rh_obj + NH;
  float* obj_probs2 = obj_probs  + (size_t)N_OBJ * NOC;
  float* keepmask   = obj_probs2 + (size_t)N_OBJ * NOC;
  float* hm   = z_rel;
  float* part = m_rel;           // m_rel region (4.19M floats) once m_rel dead
  float* part_no = rh_rel;       // rh_rel region (dead after newh_rel GEMM)
  float* fend = keepmask + (size_t)(NOC - 1) * N_OBJ;

  u16* bt = (u16*)fend;
  const int KP_HOBJ = 4256;
  const int KP_HREL = 4096;
  const int KP_MSG  = 512;
  const int KP_GRU  = 1024;
  const int KP_CLS  = 512;
  u16* p = bt;
  u16* bt_hobj_h = p; p += (size_t)H * KP_HOBJ;      u16* bt_hobj_l = p; p += (size_t)H * KP_HOBJ;
  u16* bt_hrel_h = p; p += (size_t)H * KP_HREL;      u16* bt_hrel_l = p; p += (size_t)H * KP_HREL;
  u16* bt_mrel_h = p; p += (size_t)H * KP_MSG;       u16* bt_mrel_l = p; p += (size_t)H * KP_MSG;
  u16* bt_hm_h   = p; p += (size_t)H * KP_MSG;       u16* bt_hm_l   = p; p += (size_t)H * KP_MSG;
  u16* bt_gr_h   = p; p += (size_t)2 * H * KP_GRU;   u16* bt_gr_l   = p; p += (size_t)2 * H * KP_GRU;
  u16* bt_nr_h   = p; p += (size_t)H * KP_GRU;       u16* bt_nr_l   = p; p += (size_t)H * KP_GRU;
  u16* bt_go_h   = p; p += (size_t)2 * H * KP_GRU;   u16* bt_go_l   = p; p += (size_t)2 * H * KP_GRU;
  u16* bt_no_h   = p; p += (size_t)H * KP_GRU;       u16* bt_no_l   = p; p += (size_t)H * KP_GRU;
  u16* bt_cr_h   = p; p += (size_t)128 * KP_CLS;     u16* bt_cr_l   = p; p += (size_t)128 * KP_CLS;
  u16* bt_co_h   = p; p += (size_t)256 * KP_CLS;     u16* bt_co_l   = p; p += (size_t)256 * KP_CLS;

  size_t used_b = (size_t)((char*)p - (char*)d_ws);
  used_b = (used_b + 15) & ~(size_t)15;
  float* part2 = (float*)((char*)d_ws + used_b);                 // 2*RH floats
  bool have2 = (used_b + 2 * RH * sizeof(float)) <= ws_size;

  float* out_logits = (float*)d_out;
  float* out_preds  = out_logits + (size_t)N_OBJ * NOC;
  float* out_rel    = out_preds + N_OBJ;

  dim3 blk(256);

  // ---- merged weight prep + input softmax (ONE dispatch)
  {
    PJobs pj;
    auto setj = [&](int i, const float* W1, int ld1, int K1, const float* W2, int ld2, int K2,
                    int coloff, int ncols, int N, int Kpad, u16* oh, u16* ol, int& blk0) {
      PJob& J = pj.j[i];
      J.W1 = W1; J.ld1 = ld1; J.K1 = K1; J.W2 = W2; J.ld2 = ld2; J.K2 = K2;
      J.coloff = coloff; J.ncols = ncols; J.N = N; J.Kpad = Kpad;
      J.oh = oh; J.ol = ol;
      J.nkb = (Kpad + 63) / 64;
      J.blk0 = blk0;
      blk0 += J.nkb * ((N + 63) / 64);
    };
    int b0 = 0;
    setj(0, W_obj_proj, H, OBJ_DIM, W_emb, H, NOC, 0, H, H, KP_HOBJ, bt_hobj_h, bt_hobj_l, b0);
    setj(1, W_rel_proj, H, OBJ_DIM, nullptr, 0, 0, 0, H, H, KP_HREL, bt_hrel_h, bt_hrel_l, b0);
    setj(2, W_msg_rel, H, H, nullptr, 0, 0, 0, H, H, KP_MSG, bt_mrel_h, bt_mrel_l, b0);
    setj(3, W_msg_obj, H, H, nullptr, 0, 0, 0, H, H, KP_MSG, bt_hm_h, bt_hm_l, b0);
    setj(4, W_gru_rel, 3 * H, H, U_gru_rel, 3 * H, H, 0, 2 * H, 2 * H, KP_GRU, bt_gr_h, bt_gr_l, b0);
    setj(5, W_gru_rel, 3 * H, H, U_gru_rel, 3 * H, H, 2 * H, H, H, KP_GRU, bt_nr_h, bt_nr_l, b0);
    setj(6, W_gru_obj, 3 * H, H, U_gru_obj, 3 * H, H, 0, 2 * H, 2 * H, KP_GRU, bt_go_h, bt_go_l, b0);
    setj(7, W_gru_obj, 3 * H, H, U_gru_obj, 3 * H, H, 2 * H, H, H, KP_GRU, bt_no_h, bt_no_l, b0);
    setj(8, W_cls_rel, NRC, H, nullptr, 0, 0, 0, NRC, 128, KP_CLS, bt_cr_h, bt_cr_l, b0);
    setj(9, W_cls_obj, NOC, H, nullptr, 0, 0, 0, NOC, 256, KP_CLS, bt_co_h, bt_co_l, b0);
    pj.smx_in = obj_logits;
    pj.smx_out = obj_probs;
    pj.smx_blk0 = b0;
    prep_all<<<b0 + N_OBJ, 256, 0, stream>>>(pj);
  }

#define MG(EPI, DUAL, GATH, PAIR, SPLIT, grid, M, N, K1, K2, nkt, A1, lda1, A2, lda2, \
           Bh, Bl, Bh2, Bl2, bias, C, ldc, C2, ridx, Hb, ldh, Zin, Zo, RHo, part, ktc) \
  mgemm_k<EPI, DUAL, GATH, PAIR, SPLIT><<<grid, blk, 0, stream>>>( \
      M, N, K1, K2, nkt, A1, lda1, A2, lda2, Bh, Bl, Bh2, Bl2, bias, C, ldc, C2, \
      ridx, Hb, ldh, Zin, Zo, RHo, part, ktc)

  // proj partial regions (disjoint within the 3*RH dead scratch)
  float* part_obj = part;                         // 8 x 512 x 512   = 2.10M
  float* part_rel = part + (size_t)8 * N_OBJ * H; // 2 x 8192 x 512  = 8.39M

  // h_obj partials (split-K S=8)
  MG(EPI_STORE, true, false, false, true, dim3(4, 4, 8), N_OBJ, H, OBJ_DIM, NOC, KP_HOBJ / 32,
     obj_fmaps, OBJ_DIM, obj_probs, NOC, bt_hobj_h, bt_hobj_l, nullptr, nullptr,
     nullptr, nullptr, 0, nullptr, nullptr, nullptr, 0, nullptr, nullptr, nullptr, part_obj, 17);
  // h_rel partials (split-K S=2)
  MG(EPI_STORE, false, false, false, true, dim3(4, 64, 2), R_REL, H, OBJ_DIM, 0, KP_HREL / 32,
     vr, OBJ_DIM, nullptr, 0, bt_hrel_h, bt_hrel_l, nullptr, nullptr,
     nullptr, nullptr, 0, nullptr, nullptr, nullptr, 0, nullptr, nullptr, nullptr, part_rel, 64);
  // combined reduce: h_obj then h_rel
  {
    int nb1 = (N_OBJ * H + 255) / 256;
    int nb2 = ((int)RH + 255) / 256;
    epi_reduce2x<EPI_BIAS, EPI_BIAS><<<nb1 + nb2, blk, 0, stream>>>(
        nb1,
        8, N_OBJ, H, H, part_obj, b_obj_proj, h_obj, H, nullptr, nullptr, nullptr, nullptr,
        2, R_REL, H, H, part_rel, b_rel_proj, h_rel, H, nullptr, nullptr, nullptr, nullptr);
  }

  for (int it = 0; it < T_ITERS; ++it) {
    // paired: z=0: m_rel = (h_obj[s]+h_obj[o]) @ W_msg_rel ; z=1: hm = h_rel @ W_msg_obj
    MG(EPI_STORE, false, true, true, false, dim3(4, 64, 2), R_REL, H, H, 0, KP_MSG / 32,
       h_obj, H, h_rel, H, bt_mrel_h, bt_mrel_l, bt_hm_h, bt_hm_l,
       nullptr, m_rel, H, hm, rel_inds, nullptr, 0, nullptr, nullptr, nullptr, nullptr, 0);
    m_obj_gather_k<<<N_OBJ, 256, 0, stream>>>(hm, rel_inds, m_obj);

    // GRU rel gates (512 blocks, direct EPI)
    MG(EPI_GATE, true, false, false, false, dim3(8, 64), R_REL, 2 * H, H, H, KP_GRU / 32,
       m_rel, H, h_rel, H, bt_gr_h, bt_gr_l, nullptr, nullptr,
       b_gru_rel, nullptr, 0, nullptr, nullptr, h_rel, H, nullptr, z_rel, rh_rel, nullptr, 0);

    if (have2) {
      // newh_rel partials (split-K S=2 into part2); reads m_rel, rh_rel
      MG(EPI_STORE, true, false, false, true, dim3(4, 64, 2), R_REL, H, H, H, KP_GRU / 32,
         m_rel, H, rh_rel, H, bt_nr_h, bt_nr_l, nullptr, nullptr,
         nullptr, nullptr, 0, nullptr, nullptr, nullptr, 0, nullptr, nullptr, nullptr, part2, 16);
      // GRU obj gates partials (S=8 into part = m_rel region; m_rel dead now)
      MG(EPI_STORE, true, false, false, true, dim3(8, 4, 8), N_OBJ, 2 * H, H, H, KP_GRU / 32,
         m_obj, H, h_obj, H, bt_go_h, bt_go_l, nullptr, nullptr,
         nullptr, nullptr, 0, nullptr, nullptr, nullptr, 0, nullptr, nullptr, nullptr, part, 4);
      epi_reduce<EPI_GATE><<<(N_OBJ * 2 * H + 255) / 256, blk, 0, stream>>>(
          8, N_OBJ, 2 * H, 2 * H, part, b_gru_obj, nullptr, 0, h_obj, H, nullptr, z_obj, rh_obj);
      // newh_obj partials (S=8 into part_no = rh_rel region; rh_rel dead now)
      MG(EPI_STORE, true, false, false, true, dim3(4, 4, 8), N_OBJ, H, H, H, KP_GRU / 32,
         m_obj, H, rh_obj, H, bt_no_h, bt_no_l, nullptr, nullptr,
         nullptr, nullptr, 0, nullptr, nullptr, nullptr, 0, nullptr, nullptr, nullptr, part_no, 4);
      // merged NEWH reduce (rel from part2 + obj from part_no); z_rel intact
      int nb1 = ((int)RH + 255) / 256;
      int nb2 = (N_OBJ * H + 255) / 256;
      epi_reduce2x<EPI_NEWH, EPI_NEWH><<<nb1 + nb2, blk, 0, stream>>>(
          nb1,
          2, R_REL, H, H, part2, b_gru_rel + 2 * H, h_rel, H, h_rel, z_rel, nullptr, nullptr,
          8, N_OBJ, H, H, part_no, b_gru_obj + 2 * H, h_obj, H, h_obj, z_obj, nullptr, nullptr);
    } else {
      // fallback: exact R12 sequence (direct NEWH for rel, split for obj)
      MG(EPI_NEWH, true, false, false, false, dim3(4, 64), R_REL, H, H, H, KP_GRU / 32,
         m_rel, H, rh_rel, H, bt_nr_h, bt_nr_l, nullptr, nullptr,
         b_gru_rel + 2 * H, h_rel, H, nullptr, nullptr, h_rel, H, z_rel, nullptr, nullptr, nullptr, 0);
      MG(EPI_STORE, true, false, false, true, dim3(8, 4, 8), N_OBJ, 2 * H, H, H, KP_GRU / 32,
         m_obj, H, h_obj, H, bt_go_h, bt_go_l, nullptr, nullptr,
         nullptr, nullptr, 0, nullptr, nullptr, nullptr, 0, nullptr, nullptr, nullptr, part, 4);
      epi_reduce<EPI_GATE><<<(N_OBJ * 2 * H + 255) / 256, blk, 0, stream>>>(
          8, N_OBJ, 2 * H, 2 * H, part, b_gru_obj, nullptr, 0, h_obj, H, nullptr, z_obj, rh_obj);
      MG(EPI_STORE, true, false, false, true, dim3(4, 4, 8), N_OBJ, H, H, H, KP_GRU / 32,
         m_obj, H, rh_obj, H, bt_no_h, bt_no_l, nullptr, nullptr,
         nullptr, nullptr, 0, nullptr, nullptr, nullptr, 0, nullptr, nullptr, nullptr, part, 4);
      epi_reduce<EPI_NEWH><<<(N_OBJ * H + 255) / 256, blk, 0, stream>>>(
          8, N_OBJ, H, H, part, b_gru_obj + 2 * H, h_obj, H, h_obj, H, z_obj, nullptr, nullptr);
    }
  }

  // classifier partial regions (scratch all dead now)
  float* part_crel = part;                               // 4 x 8192 x 128 = 4.19M
  float* part_cobj = part + (size_t)4 * R_REL * 128;     // 8 x 512 x 256  = 1.05M

  // rel_logits partials (N=51, padded bt to 128, split-K S=4)
  MG(EPI_STORE, false, false, false, true, dim3(1, 64, 4), R_REL, NRC, H, 0, KP_CLS / 32,
     h_rel, H, nullptr, 0, bt_cr_h, bt_cr_l, nullptr, nullptr,
     nullptr, nullptr, 0, nullptr, nullptr, nullptr, 0, nullptr, nullptr, nullptr, part_crel, 4);
  // obj_logits partials (N=151, padded bt to 256, split-K S=8)
  MG(EPI_STORE, false, false, false, true, dim3(2, 4, 8), N_OBJ, NOC, H, 0, KP_CLS / 32,
     h_obj, H, nullptr, 0, bt_co_h, bt_co_l, nullptr, nullptr,
     nullptr, nullptr, 0, nullptr, nullptr, nullptr, 0, nullptr, nullptr, nullptr, part_cobj, 2);
  // combined classifier reduce
  {
    int nb1 = (R_REL * 128 + 255) / 256;
    int nb2 = (N_OBJ * 256 + 255) / 256;
    epi_reduce2x<EPI_BIAS, EPI_BIAS><<<nb1 + nb2, blk, 0, stream>>>(
        nb1,
        4, R_REL, NRC, 128, part_crel, b_cls_rel, out_rel, NRC, nullptr, nullptr, nullptr, nullptr,
        8, N_OBJ, NOC, 256, part_cobj, b_cls_obj, out_logits, NOC, nullptr, nullptr, nullptr, nullptr);
  }

  // softmax -> NMS -> preds
  softmax_k<<<N_OBJ, 256, 0, stream>>>(out_logits, obj_probs2);
  nms_k<<<NOC - 1, 512, 0, stream>>>(obj_probs2, boxes, keepmask);
  pred_k<<<2, 256, 0, stream>>>(obj_probs2, keepmask, out_preds);
}

// Round 18
// 1383.567 us; speedup vs baseline: 1.0126x; 1.0126x over previous
//
#include <hip/hip_runtime.h>
#include <math.h>

#define OPI 64
#define RPI 1024
#define N_OBJ 512       // B*OPI
#define R_REL 8192      // B*RPI
#define OBJ_DIM 4096
#define H 512
#define NOC 151
#define NRC 51
#define T_ITERS 3
#define IOU_THRESH 0.3f

typedef unsigned short u16;
typedef unsigned int u32;
typedef unsigned long long u64;
typedef __attribute__((ext_vector_type(4))) float f32x4;
typedef __attribute__((ext_vector_type(8))) short bf16x8;
typedef __attribute__((ext_vector_type(2))) unsigned int u32x2;
typedef __attribute__((ext_vector_type(8))) short s16x8;

enum { EPI_STORE = 0, EPI_BIAS = 1, EPI_GATE = 3, EPI_NEWH = 4 };

__device__ inline u16 f2bf(float x) {
  u32 u = __float_as_uint(x);
  u32 r = (u + 0x7fffu + ((u >> 16) & 1u)) >> 16;
  return (u16)r;
}
__device__ inline float bf2f(u16 h) { return __uint_as_float(((u32)h) << 16); }
// HW packed fp32->bf16 (RTNE, matches f2bf): lo half = cvt(a), hi half = cvt(b)
__device__ inline u32 cvtpk(float a, float b) {
  u32 r;
  asm("v_cvt_pk_bf16_f32 %0, %1, %2" : "=v"(r) : "v"(a), "v"(b));
  return r;
}

// ---------------------------------------------------------------------------
// Merged weight prep (10 transpose/split jobs) + input softmax, ONE dispatch.
// ---------------------------------------------------------------------------
struct PJob {
  const float* W1; const float* W2; u16* oh; u16* ol;
  int ld1, K1, ld2, K2, coloff, ncols, N, Kpad, blk0, nkb;
};
struct PJobs { PJob j[10]; const float* smx_in; float* smx_out; int smx_blk0; };

__global__ __launch_bounds__(256) void prep_all(PJobs jobs) {
  __shared__ float tile[64][65];
  __shared__ float red[4];
  const int bid = blockIdx.x;
  const int t = threadIdx.x;

  if (bid >= jobs.smx_blk0) {           // ---- softmax rows
    int row = bid - jobs.smx_blk0;
    const float* X = jobs.smx_in;
    float* P = jobs.smx_out;
    float x = (t < NOC) ? X[row * NOC + t] : -3.4e38f;
    float m = x;
#pragma unroll
    for (int o = 32; o > 0; o >>= 1) m = fmaxf(m, __shfl_xor(m, o, 64));
    if ((t & 63) == 0) red[t >> 6] = m;
    __syncthreads();
    float mm = fmaxf(fmaxf(red[0], red[1]), fmaxf(red[2], red[3]));
    float e = (t < NOC) ? expf(x - mm) : 0.f;
    float s = e;
#pragma unroll
    for (int o = 32; o > 0; o >>= 1) s += __shfl_xor(s, o, 64);
    __syncthreads();
    if ((t & 63) == 0) red[t >> 6] = s;
    __syncthreads();
    float ss = red[0] + red[1] + red[2] + red[3];
    if (t < NOC) P[row * NOC + t] = e / ss;
    return;
  }

  int ji = 0;
#pragma unroll
  for (int i = 1; i < 10; ++i) if (bid >= jobs.j[i].blk0) ji = i;
  const PJob J = jobs.j[ji];
  const int local = bid - J.blk0;
  const int k0 = (local % J.nkb) * 64;
  const int n0 = (local / J.nkb) * 64;
  const int lane = t & 63;
  const int w = t >> 6;
#pragma unroll
  for (int p = 0; p < 16; ++p) {
    int kl = w * 16 + p;
    int k = k0 + kl;
    int n = n0 + lane;
    float v = 0.f;
    if (n < J.ncols) {
      if (k < J.K1) v = J.W1[(size_t)k * J.ld1 + J.coloff + n];
      else if (k - J.K1 < J.K2) v = J.W2[(size_t)(k - J.K1) * J.ld2 + J.coloff + n];
    }
    tile[kl][lane] = v;
  }
  __syncthreads();
#pragma unroll
  for (int p = 0; p < 16; ++p) {
    int nl = w * 16 + p;
    int n = n0 + nl;
    int k = k0 + lane;
    if (n < J.N && k < J.Kpad) {
      float v = tile[lane][nl];
      u16 h = f2bf(v);
      J.oh[(size_t)n * J.Kpad + k] = h;
      J.ol[(size_t)n * J.Kpad + k] = f2bf(v - bf2f(h));
    }
  }
}

// ---------------------------------------------------------------------------
// Split-bf16 MFMA GEMM (R16 core with a deeper A-prefetch pipeline:
// stageA moved BEFORE the MFMA block so loadA(k+2) issues under iteration k's
// MFMAs -> A-load cover window ~1.5 iterations instead of ~0.5; no extra
// registers. B stays 1-deep (small L2-hot weights).
// ---------------------------------------------------------------------------
template<int EPI, bool DUAL, bool GATHER, bool PAIR, bool SPLIT>
__global__ __launch_bounds__(256, 2) void mgemm_k(
    int M, int N, int K1, int K2, int nkt,
    const float* __restrict__ A1, int lda1,
    const float* __restrict__ A2, int lda2,
    const u16* __restrict__ Bth, const u16* __restrict__ Btl,
    const u16* __restrict__ Bth2, const u16* __restrict__ Btl2,
    const float* __restrict__ bias,
    float* __restrict__ C, int ldc, float* __restrict__ C2,
    const int* __restrict__ ridx,
    const float* __restrict__ Hb, int ldh,
    const float* __restrict__ Zin,
    float* __restrict__ Zout, float* __restrict__ RHout,
    float* __restrict__ part, int ktchunk)
{
  __shared__ u16 lAh[2][128 * 32];
  __shared__ u16 lAl[2][128 * 32];
  __shared__ u16 lBh[2][128 * 32];
  __shared__ u16 lBl[2][128 * 32];
  const int t = threadIdx.x;
  const int lane = t & 63;
  const int wid = t >> 6;          // 0..3
  const int wm = wid >> 1;         // 0..1 (64-row half)
  const int wn = wid & 1;          // 0..1 (64-col half)

  // bijective XCD-aware swizzle over (x,y); all grids have nbx*nby % 8 == 0
  const int nbx = gridDim.x, nby = gridDim.y;
  const int nwg = nbx * nby;
  int orig = blockIdx.y * nbx + blockIdx.x;
  int lid = (orig & 7) * (nwg >> 3) + (orig >> 3);
  const int bx = lid % nbx;
  const int by = lid / nbx;

  const int m0 = by * 128;
  const int n0 = bx * 128;
  const int Kpad = nkt * 32;

  const float* A1p = A1; int ldap = lda1;
  const u16* Bhp = Bth; const u16* Blp = Btl;
  float* Cp = C;
  bool gath = GATHER;
  if (PAIR && blockIdx.z == 1) {
    A1p = A2; ldap = lda2; Bhp = Bth2; Blp = Btl2; Cp = C2; gath = false;
  }

  f32x4 acc[4][4];
#pragma unroll
  for (int m = 0; m < 4; ++m)
#pragma unroll
    for (int n = 0; n < 4; ++n) acc[m][n] = f32x4{0.f, 0.f, 0.f, 0.f};

  const int a_row = t >> 3;        // 0..31 (+i*32)
  const int a_kq  = t & 7;
  int g_si[4], g_oi[4];
  if (gath) {
#pragma unroll
    for (int i = 0; i < 4; ++i) {
      int gm = m0 + a_row + i * 32;
      g_si[i] = ridx[gm * 3 + 1];
      g_oi[i] = ridx[gm * 3 + 2];
    }
  }
  const int b_row  = t >> 2;       // 0..63 (+i*64)
  const int b_slot = t & 3;

  int ktb = 0, kte = nkt;
  if (SPLIT) {
    ktb = blockIdx.z * ktchunk;
    kte = min(nkt, ktb + ktchunk);
  }

  float4 rA[4];
  s16x8 rBh[2], rBl[2];

  auto loadA = [&](int kt) {
    const int gk = kt * 32 + a_kq * 4;
#pragma unroll
    for (int i = 0; i < 4; ++i) {
      const int gm = m0 + a_row + i * 32;
      if (gath) {
        float4 va = *(const float4*)&A1p[(size_t)g_si[i] * ldap + gk];
        float4 vb = *(const float4*)&A1p[(size_t)g_oi[i] * ldap + gk];
        rA[i] = make_float4(va.x + vb.x, va.y + vb.y, va.z + vb.z, va.w + vb.w);
      } else if (!DUAL) {
        rA[i] = *(const float4*)&A1p[(size_t)gm * ldap + gk];
      } else {
        if (gk + 3 < K1) {
          rA[i] = *(const float4*)&A1p[(size_t)gm * lda1 + gk];
        } else if (gk >= K1 && gk + 3 < K1 + K2 && (lda2 & 3) == 0) {
          rA[i] = *(const float4*)&A2[(size_t)gm * lda2 + (gk - K1)];
        } else {
          float xs[4];
#pragma unroll
          for (int e = 0; e < 4; ++e) {
            int gke = gk + e;
            float xv = 0.f;
            if (gke < K1) xv = A1p[(size_t)gm * lda1 + gke];
            else if (gke < K1 + K2) xv = A2[(size_t)gm * lda2 + (gke - K1)];
            xs[e] = xv;
          }
          rA[i] = make_float4(xs[0], xs[1], xs[2], xs[3]);
        }
      }
    }
  };
  auto loadB = [&](int kt) {
#pragma unroll
    for (int i = 0; i < 2; ++i) {
      const size_t goff = (size_t)(n0 + b_row + i * 64) * Kpad + kt * 32 + b_slot * 8;
      rBh[i] = *(const s16x8*)&Bhp[goff];
      rBl[i] = *(const s16x8*)&Blp[goff];
    }
  };
  auto stageA = [&](int buf) {
#pragma unroll
    for (int i = 0; i < 4; ++i) {
      const int row = a_row + i * 32;
      float x0 = rA[i].x, x1 = rA[i].y, x2 = rA[i].z, x3 = rA[i].w;
      u32 h01 = cvtpk(x0, x1);
      u32 h23 = cvtpk(x2, x3);
      float r0 = __uint_as_float(h01 << 16);
      float r1 = __uint_as_float(h01 & 0xffff0000u);
      float r2 = __uint_as_float(h23 << 16);
      float r3 = __uint_as_float(h23 & 0xffff0000u);
      u32 l01 = cvtpk(x0 - r0, x1 - r1);
      u32 l23 = cvtpk(x2 - r2, x3 - r3);
      const int base = row * 32 + (((a_kq >> 1) ^ ((row >> 1) & 3)) << 3) + (a_kq & 1) * 4;
      *reinterpret_cast<u32x2*>(&lAh[buf][base]) = u32x2{h01, h23};
      *reinterpret_cast<u32x2*>(&lAl[buf][base]) = u32x2{l01, l23};
    }
  };
  auto stageB = [&](int buf) {
#pragma unroll
    for (int i = 0; i < 2; ++i) {
      const int row = b_row + i * 64;
      const int base = row * 32 + ((b_slot ^ ((row >> 1) & 3)) << 3);
      *reinterpret_cast<s16x8*>(&lBh[buf][base]) = rBh[i];
      *reinterpret_cast<s16x8*>(&lBl[buf][base]) = rBl[i];
    }
  };

  const int fr = lane & 15;
  const int kg = lane >> 4;

  if (ktb < kte) {
    loadA(ktb);
    loadB(ktb);
    stageA(0);
    stageB(0);
    if (ktb + 1 < kte) loadA(ktb + 1);   // A prefetch now runs one stage ahead
    __syncthreads();
    const int nk = kte - ktb;
    for (int kk = 0; kk < nk; ++kk) {
      const int cur = kk & 1;
      const bool more = (kk + 1 < nk);
      if (more) loadB(ktb + kk + 1);     // B 1-deep (L2-hot weights)
      bf16x8 ah[4], al[4], bh[4], bl[4];
#pragma unroll
      for (int m = 0; m < 4; ++m) {
        const int r = wm * 64 + m * 16 + fr;
        const int addr = r * 32 + ((kg ^ ((r >> 1) & 3)) << 3);
        ah[m] = *reinterpret_cast<const bf16x8*>(&lAh[cur][addr]);
        al[m] = *reinterpret_cast<const bf16x8*>(&lAl[cur][addr]);
      }
#pragma unroll
      for (int n = 0; n < 4; ++n) {
        const int r = wn * 64 + n * 16 + fr;
        const int addr = r * 32 + ((kg ^ ((r >> 1) & 3)) << 3);
        bh[n] = *reinterpret_cast<const bf16x8*>(&lBh[cur][addr]);
        bl[n] = *reinterpret_cast<const bf16x8*>(&lBl[cur][addr]);
      }
      if (more) stageA(cur ^ 1);          // consume rA (kt=kk+1) -> frees rA
      if (kk + 2 < nk) loadA(ktb + kk + 2);  // issue 2-ahead A load under MFMAs
      __builtin_amdgcn_s_setprio(1);
#pragma unroll
      for (int m = 0; m < 4; ++m)
#pragma unroll
        for (int n = 0; n < 4; ++n) {
          acc[m][n] = __builtin_amdgcn_mfma_f32_16x16x32_bf16(ah[m], bh[n], acc[m][n], 0, 0, 0);
          acc[m][n] = __builtin_amdgcn_mfma_f32_16x16x32_bf16(ah[m], bl[n], acc[m][n], 0, 0, 0);
          acc[m][n] = __builtin_amdgcn_mfma_f32_16x16x32_bf16(al[m], bh[n], acc[m][n], 0, 0, 0);
        }
      __builtin_amdgcn_s_setprio(0);
      if (more) stageB(cur ^ 1);
      __syncthreads();
    }
  }

  // ---- epilogue (C/D layout: col = lane&15, row = (lane>>4)*4 + j)
  const int col = lane & 15;
  const int rb = (lane >> 4) * 4;
  if (SPLIT) {
    const int Npad = gridDim.x * 128;
    float* pp = part + (size_t)blockIdx.z * M * Npad;
#pragma unroll
    for (int m = 0; m < 4; ++m)
#pragma unroll
      for (int n = 0; n < 4; ++n) {
        const int gn = n0 + wn * 64 + n * 16 + col;
#pragma unroll
        for (int j = 0; j < 4; ++j) {
          const int gm = m0 + wm * 64 + m * 16 + rb + j;
          pp[(size_t)gm * Npad + gn] = acc[m][n][j];
        }
      }
    return;
  }
#pragma unroll
  for (int m = 0; m < 4; ++m) {
#pragma unroll
    for (int n = 0; n < 4; ++n) {
      const int gn = n0 + wn * 64 + n * 16 + col;
      if (gn >= N) continue;
#pragma unroll
      for (int j = 0; j < 4; ++j) {
        const int gm = m0 + wm * 64 + m * 16 + rb + j;
        float v = acc[m][n][j];
        if (EPI == EPI_STORE) {
          Cp[(size_t)gm * ldc + gn] = v;
        } else if (EPI == EPI_BIAS) {
          Cp[(size_t)gm * ldc + gn] = v + bias[gn];
        } else if (EPI == EPI_GATE) {
          float g = 1.f / (1.f + expf(-(v + bias[gn])));
          int half = N >> 1;
          if (gn < half) Zout[(size_t)gm * half + gn] = g;
          else RHout[(size_t)gm * half + (gn - half)] = g * Hb[(size_t)gm * ldh + (gn - half)];
        } else if (EPI == EPI_NEWH) {
          float nv = tanhf(v + bias[gn]);
          float z = Zin[(size_t)gm * N + gn];
          float h = Hb[(size_t)gm * ldh + gn];
          Cp[(size_t)gm * ldc + gn] = (1.f - z) * h + z * nv;
        }
      }
    }
  }
}

// ---------------------------------------------------------------------------
// Split-K reduce + epilogue (single and dual-job).
// ---------------------------------------------------------------------------
template<int EPI>
__device__ inline void reduce_body(int blk, int S, int M, int N, int Npad,
    const float* __restrict__ part, const float* __restrict__ bias,
    float* __restrict__ C, int ldc,
    const float* __restrict__ Hb, int ldh,
    const float* __restrict__ Zin,
    float* __restrict__ Zout, float* __restrict__ RHout)
{
  int idx = blk * 256 + (int)threadIdx.x;
  if (idx >= M * Npad) return;
  int m = idx / Npad;
  int n = idx - m * Npad;
  if (n >= N) return;
  size_t stride = (size_t)M * Npad;
  float v = 0.f;
  for (int s = 0; s < S; ++s) v += part[s * stride + idx];
  if (EPI == EPI_BIAS) {
    C[(size_t)m * ldc + n] = v + bias[n];
  } else if (EPI == EPI_GATE) {
    float g = 1.f / (1.f + expf(-(v + bias[n])));
    int half = N >> 1;
    if (n < half) Zout[(size_t)m * half + n] = g;
    else RHout[(size_t)m * half + (n - half)] = g * Hb[(size_t)m * ldh + (n - half)];
  } else if (EPI == EPI_NEWH) {
    float nv = tanhf(v + bias[n]);
    float z = Zin[(size_t)m * N + n];
    float h = Hb[(size_t)m * ldh + n];
    C[(size_t)m * ldc + n] = (1.f - z) * h + z * nv;
  }
}

template<int EPI>
__global__ __launch_bounds__(256) void epi_reduce(
    int S, int M, int N, int Npad,
    const float* __restrict__ part, const float* __restrict__ bias,
    float* __restrict__ C, int ldc,
    const float* __restrict__ Hb, int ldh,
    const float* __restrict__ Zin,
    float* __restrict__ Zout, float* __restrict__ RHout)
{
  reduce_body<EPI>(blockIdx.x, S, M, N, Npad, part, bias, C, ldc, Hb, ldh, Zin, Zout, RHout);
}

template<int E1, int E2>
__global__ __launch_bounds__(256) void epi_reduce2x(
    int nblk1,
    int S1, int M1, int N1, int P1, const float* p1, const float* b1, float* C1, int l1,
    const float* Hb1, const float* Z1, float* Zo1, float* Rh1,
    int S2, int M2, int N2, int P2, const float* p2, const float* b2, float* C2, int l2,
    const float* Hb2, const float* Z2, float* Zo2, float* Rh2)
{
  if ((int)blockIdx.x < nblk1)
    reduce_body<E1>(blockIdx.x, S1, M1, N1, P1, p1, b1, C1, l1, Hb1, H, Z1, Zo1, Rh1);
  else
    reduce_body<E2>(blockIdx.x - nblk1, S2, M2, N2, P2, p2, b2, C2, l2, Hb2, H, Z2, Zo2, Rh2);
}

// row softmax over NOC=151 columns, one block per row
__global__ __launch_bounds__(256) void softmax_k(const float* __restrict__ X,
                                                 float* __restrict__ P)
{
  int row = blockIdx.x;
  int t = threadIdx.x;
  __shared__ float red[4];
  float x = (t < NOC) ? X[row * NOC + t] : -3.4e38f;
  float m = x;
#pragma unroll
  for (int o = 32; o > 0; o >>= 1) m = fmaxf(m, __shfl_xor(m, o, 64));
  if ((t & 63) == 0) red[t >> 6] = m;
  __syncthreads();
  float mm = fmaxf(fmaxf(red[0], red[1]), fmaxf(red[2], red[3]));
  float e = (t < NOC) ? expf(x - mm) : 0.f;
  float s = e;
#pragma unroll
  for (int o = 32; o > 0; o >>= 1) s += __shfl_xor(s, o, 64);
  __syncthreads();
  if ((t & 63) == 0) red[t >> 6] = s;
  __syncthreads();
  float ss = red[0] + red[1] + red[2] + red[3];
  if (t < NOC) P[row * NOC + t] = e / ss;
}

// deterministic scatter-free m_obj
__global__ __launch_bounds__(256) void m_obj_gather_k(const float* __restrict__ hm,
                                                      const int* __restrict__ ridx,
                                                      float* __restrict__ m_obj)
{
  int n = blockIdx.x;
  int im = n >> 6;
  int col = threadIdx.x;
  float acc0 = 0.f, acc1 = 0.f;
  int r0 = im * RPI, r1 = r0 + RPI;
  for (int r = r0; r < r1; ++r) {
    int s = ridx[r * 3 + 1];
    int o = ridx[r * 3 + 2];
    int cnt = (s == n) + (o == n);
    if (cnt) {
      float f = (float)cnt;
      acc0 = fmaf(f, hm[r * H + col], acc0);
      acc1 = fmaf(f, hm[r * H + col + 256], acc1);
    }
  }
  m_obj[n * H + col] = acc0;
  m_obj[n * H + col + 256] = acc1;
}

// ---------------------------------------------------------------------------
// Per-class NMS: stable bitonic sort + bitmask suppression.
// ---------------------------------------------------------------------------
__global__ __launch_bounds__(512) void nms_k(const float* __restrict__ probs2,
                                             const float* __restrict__ boxes,
                                             float* __restrict__ keepmask)
{
  int c = blockIdx.x + 1;
  int t = threadIdx.x;
  __shared__ float sc[512];
  __shared__ int   si[512];
  __shared__ float bx0[512], by0[512], bx1[512], by1[512], sar[512];
  __shared__ u64   msk[512][8];
  __shared__ u64   keepw_s[8];

  sc[t] = probs2[t * NOC + c];
  si[t] = t;
  __syncthreads();

  for (int k = 2; k <= 512; k <<= 1) {
    for (int j = k >> 1; j > 0; j >>= 1) {
      int p = t ^ j;
      if (p > t) {
        float s1 = sc[t], s2 = sc[p];
        int   i1 = si[t], i2 = si[p];
        bool tBefore = (s1 > s2) || (s1 == s2 && i1 < i2);
        bool up = ((t & k) == 0);
        if (up != tBefore) { sc[t] = s2; sc[p] = s1; si[t] = i2; si[p] = i1; }
      }
      __syncthreads();
    }
  }

  {
    const float* b = &boxes[(si[t] * NOC + c) * 4];
    float x0 = b[0], y0 = b[1], x1 = b[2], y1 = b[3];
    bx0[t] = x0; by0[t] = y0; bx1[t] = x1; by1[t] = y1;
    sar[t] = (x1 - x0) * (y1 - y0);
  }
  __syncthreads();

  {
    const float x0 = bx0[t], y0 = by0[t], x1 = bx1[t], y1 = by1[t], ar = sar[t];
#pragma unroll
    for (int w = 0; w < 8; ++w) {
      u64 bits = 0ull;
#pragma unroll 4
      for (int b = 0; b < 64; ++b) {
        const int j = w * 64 + b;
        float lx = fmaxf(x0, bx0[j]);
        float ly = fmaxf(y0, by0[j]);
        float rx = fminf(x1, bx1[j]);
        float ry = fminf(y1, by1[j]);
        float ww = fmaxf(rx - lx, 0.f);
        float hh = fmaxf(ry - ly, 0.f);
        float inter = ww * hh;
        float iou = inter / (ar + sar[j] - inter + 1e-9f);
        bits |= ((u64)((j > t) && (iou > IOU_THRESH))) << b;
      }
      msk[t][w] = bits;
    }
  }
  __syncthreads();

  if (t < 64) {
    const int w = t & 7;
    u64 keepw = ~0ull;
    u64 m = msk[0][w];
    for (int i = 0; i < 512; ++i) {
      u64 mn = (i + 1 < 512) ? msk[i + 1][w] : 0ull;
      u64 kw = __shfl(keepw, i >> 6, 64);
      if ((kw >> (i & 63)) & 1ull) keepw &= ~m;
      m = mn;
    }
    if (t < 8) keepw_s[t] = keepw;
  }
  __syncthreads();

  const u64 kw = keepw_s[t >> 6];
  keepmask[(c - 1) * N_OBJ + si[t]] = ((kw >> (t & 63)) & 1ull) ? 1.f : 0.f;
}

__global__ void pred_k(const float* __restrict__ probs2,
                       const float* __restrict__ keepmask,
                       float* __restrict__ out)
{
  int i = threadIdx.x + blockIdx.x * 256;
  if (i >= N_OBJ) return;
  float best = -1.f;
  int bc = 0;
  for (int c = 0; c < NOC - 1; ++c) {
    float v = keepmask[c * N_OBJ + i] * probs2[i * NOC + c + 1];
    if (v > best) { best = v; bc = c; }
  }
  out[i] = (float)(bc + 1);
}

extern "C" void kernel_launch(void* const* d_in, const int* in_sizes, int n_in,
                              void* d_out, int out_size, void* d_ws, size_t ws_size,
                              hipStream_t stream) {
  const float* obj_fmaps  = (const float*)d_in[1];
  const float* obj_logits = (const float*)d_in[2];
  const int*   rel_inds   = (const int*)d_in[3];
  const float* vr         = (const float*)d_in[4];
  const float* boxes      = (const float*)d_in[5];
  const float* W_obj_proj = (const float*)d_in[6];
  const float* b_obj_proj = (const float*)d_in[7];
  const float* W_rel_proj = (const float*)d_in[8];
  const float* b_rel_proj = (const float*)d_in[9];
  const float* W_emb      = (const float*)d_in[10];
  const float* W_msg_rel  = (const float*)d_in[11];
  const float* W_msg_obj  = (const float*)d_in[12];
  const float* W_gru_obj  = (const float*)d_in[13];
  const float* U_gru_obj  = (const float*)d_in[14];
  const float* b_gru_obj  = (const float*)d_in[15];
  const float* W_gru_rel  = (const float*)d_in[16];
  const float* U_gru_rel  = (const float*)d_in[17];
  const float* b_gru_rel  = (const float*)d_in[18];
  const float* W_cls_rel  = (const float*)d_in[19];
  const float* b_cls_rel  = (const float*)d_in[20];
  const float* W_cls_obj  = (const float*)d_in[21];
  const float* b_cls_obj  = (const float*)d_in[22];

  float* ws = (float*)d_ws;
  const size_t RH = (size_t)R_REL * H;     // 4,194,304
  const size_t NH = (size_t)N_OBJ * H;
  float* h_rel  = ws;
  float* m_rel  = h_rel  + RH;
  float* z_rel  = m_rel  + RH;   // aliased with hm
  float* rh_rel = z_rel  + RH;
  float* h_obj  = rh_rel + RH;
  float* m_obj  = h_obj  + NH;
  float* z_obj  = m_obj  + NH;
  float* rh_obj = z_obj  + NH;
  float* obj_probs  = rh_obj + NH;
  float* obj_probs2 = obj_probs  + (size_t)N_OBJ * NOC;
  float* keepmask   = obj_probs2 + (size_t)N_OBJ * NOC;
  float* hm   = z_rel;
  float* part = m_rel;           // m_rel region (4.19M floats) once m_rel dead
  float* part_no = rh_rel;       // rh_rel region (dead after newh_rel GEMM)
  float* fend = keepmask + (size_t)(NOC - 1) * N_OBJ;

  u16* bt = (u16*)fend;
  const int KP_HOBJ = 4256;
  const int KP_HREL = 4096;
  const int KP_MSG  = 512;
  const int KP_GRU  = 1024;
  const int KP_CLS  = 512;
  u16* p = bt;
  u16* bt_hobj_h = p; p += (size_t)H * KP_HOBJ;      u16* bt_hobj_l = p; p += (size_t)H * KP_HOBJ;
  u16* bt_hrel_h = p; p += (size_t)H * KP_HREL;      u16* bt_hrel_l = p; p += (size_t)H * KP_HREL;
  u16* bt_mrel_h = p; p += (size_t)H * KP_MSG;       u16* bt_mrel_l = p; p += (size_t)H * KP_MSG;
  u16* bt_hm_h   = p; p += (size_t)H * KP_MSG;       u16* bt_hm_l   = p; p += (size_t)H * KP_MSG;
  u16* bt_gr_h   = p; p += (size_t)2 * H * KP_GRU;   u16* bt_gr_l   = p; p += (size_t)2 * H * KP_GRU;
  u16* bt_nr_h   = p; p += (size_t)H * KP_GRU;       u16* bt_nr_l   = p; p += (size_t)H * KP_GRU;
  u16* bt_go_h   = p; p += (size_t)2 * H * KP_GRU;   u16* bt_go_l   = p; p += (size_t)2 * H * KP_GRU;
  u16* bt_no_h   = p; p += (size_t)H * KP_GRU;       u16* bt_no_l   = p; p += (size_t)H * KP_GRU;
  u16* bt_cr_h   = p; p += (size_t)128 * KP_CLS;     u16* bt_cr_l   = p; p += (size_t)128 * KP_CLS;
  u16* bt_co_h   = p; p += (size_t)256 * KP_CLS;     u16* bt_co_l   = p; p += (size_t)256 * KP_CLS;

  size_t used_b = (size_t)((char*)p - (char*)d_ws);
  used_b = (used_b + 15) & ~(size_t)15;
  float* part2 = (float*)((char*)d_ws + used_b);                 // 2*RH floats
  bool have2 = (used_b + 2 * RH * sizeof(float)) <= ws_size;

  float* out_logits = (float*)d_out;
  float* out_preds  = out_logits + (size_t)N_OBJ * NOC;
  float* out_rel    = out_preds + N_OBJ;

  dim3 blk(256);

  // ---- merged weight prep + input softmax (ONE dispatch)
  {
    PJobs pj;
    auto setj = [&](int i, const float* W1, int ld1, int K1, const float* W2, int ld2, int K2,
                    int coloff, int ncols, int N, int Kpad, u16* oh, u16* ol, int& blk0) {
      PJob& J = pj.j[i];
      J.W1 = W1; J.ld1 = ld1; J.K1 = K1; J.W2 = W2; J.ld2 = ld2; J.K2 = K2;
      J.coloff = coloff; J.ncols = ncols; J.N = N; J.Kpad = Kpad;
      J.oh = oh; J.ol = ol;
      J.nkb = (Kpad + 63) / 64;
      J.blk0 = blk0;
      blk0 += J.nkb * ((N + 63) / 64);
    };
    int b0 = 0;
    setj(0, W_obj_proj, H, OBJ_DIM, W_emb, H, NOC, 0, H, H, KP_HOBJ, bt_hobj_h, bt_hobj_l, b0);
    setj(1, W_rel_proj, H, OBJ_DIM, nullptr, 0, 0, 0, H, H, KP_HREL, bt_hrel_h, bt_hrel_l, b0);
    setj(2, W_msg_rel, H, H, nullptr, 0, 0, 0, H, H, KP_MSG, bt_mrel_h, bt_mrel_l, b0);
    setj(3, W_msg_obj, H, H, nullptr, 0, 0, 0, H, H, KP_MSG, bt_hm_h, bt_hm_l, b0);
    setj(4, W_gru_rel, 3 * H, H, U_gru_rel, 3 * H, H, 0, 2 * H, 2 * H, KP_GRU, bt_gr_h, bt_gr_l, b0);
    setj(5, W_gru_rel, 3 * H, H, U_gru_rel, 3 * H, H, 2 * H, H, H, KP_GRU, bt_nr_h, bt_nr_l, b0);
    setj(6, W_gru_obj, 3 * H, H, U_gru_obj, 3 * H, H, 0, 2 * H, 2 * H, KP_GRU, bt_go_h, bt_go_l, b0);
    setj(7, W_gru_obj, 3 * H, H, U_gru_obj, 3 * H, H, 2 * H, H, H, KP_GRU, bt_no_h, bt_no_l, b0);
    setj(8, W_cls_rel, NRC, H, nullptr, 0, 0, 0, NRC, 128, KP_CLS, bt_cr_h, bt_cr_l, b0);
    setj(9, W_cls_obj, NOC, H, nullptr, 0, 0, 0, NOC, 256, KP_CLS, bt_co_h, bt_co_l, b0);
    pj.smx_in = obj_logits;
    pj.smx_out = obj_probs;
    pj.smx_blk0 = b0;
    prep_all<<<b0 + N_OBJ, 256, 0, stream>>>(pj);
  }

#define MG(EPI, DUAL, GATH, PAIR, SPLIT, grid, M, N, K1, K2, nkt, A1, lda1, A2, lda2, \
           Bh, Bl, Bh2, Bl2, bias, C, ldc, C2, ridx, Hb, ldh, Zin, Zo, RHo, part, ktc) \
  mgemm_k<EPI, DUAL, GATH, PAIR, SPLIT><<<grid, blk, 0, stream>>>( \
      M, N, K1, K2, nkt, A1, lda1, A2, lda2, Bh, Bl, Bh2, Bl2, bias, C, ldc, C2, \
      ridx, Hb, ldh, Zin, Zo, RHo, part, ktc)

  // proj partial regions (disjoint within the 3*RH dead scratch)
  float* part_obj = part;                         // 8 x 512 x 512   = 2.10M
  float* part_rel = part + (size_t)8 * N_OBJ * H; // 2 x 8192 x 512  = 8.39M

  // h_obj partials (split-K S=8)
  MG(EPI_STORE, true, false, false, true, dim3(4, 4, 8), N_OBJ, H, OBJ_DIM, NOC, KP_HOBJ / 32,
     obj_fmaps, OBJ_DIM, obj_probs, NOC, bt_hobj_h, bt_hobj_l, nullptr, nullptr,
     nullptr, nullptr, 0, nullptr, nullptr, nullptr, 0, nullptr, nullptr, nullptr, part_obj, 17);
  // h_rel partials (split-K S=2)
  MG(EPI_STORE, false, false, false, true, dim3(4, 64, 2), R_REL, H, OBJ_DIM, 0, KP_HREL / 32,
     vr, OBJ_DIM, nullptr, 0, bt_hrel_h, bt_hrel_l, nullptr, nullptr,
     nullptr, nullptr, 0, nullptr, nullptr, nullptr, 0, nullptr, nullptr, nullptr, part_rel, 64);
  // combined reduce: h_obj then h_rel
  {
    int nb1 = (N_OBJ * H + 255) / 256;
    int nb2 = ((int)RH + 255) / 256;
    epi_reduce2x<EPI_BIAS, EPI_BIAS><<<nb1 + nb2, blk, 0, stream>>>(
        nb1,
        8, N_OBJ, H, H, part_obj, b_obj_proj, h_obj, H, nullptr, nullptr, nullptr, nullptr,
        2, R_REL, H, H, part_rel, b_rel_proj, h_rel, H, nullptr, nullptr, nullptr, nullptr);
  }

  for (int it = 0; it < T_ITERS; ++it) {
    // paired: z=0: m_rel = (h_obj[s]+h_obj[o]) @ W_msg_rel ; z=1: hm = h_rel @ W_msg_obj
    MG(EPI_STORE, false, true, true, false, dim3(4, 64, 2), R_REL, H, H, 0, KP_MSG / 32,
       h_obj, H, h_rel, H, bt_mrel_h, bt_mrel_l, bt_hm_h, bt_hm_l,
       nullptr, m_rel, H, hm, rel_inds, nullptr, 0, nullptr, nullptr, nullptr, nullptr, 0);
    m_obj_gather_k<<<N_OBJ, 256, 0, stream>>>(hm, rel_inds, m_obj);

    // GRU rel gates (512 blocks, direct EPI)
    MG(EPI_GATE, true, false, false, false, dim3(8, 64), R_REL, 2 * H, H, H, KP_GRU / 32,
       m_rel, H, h_rel, H, bt_gr_h, bt_gr_l, nullptr, nullptr,
       b_gru_rel, nullptr, 0, nullptr, nullptr, h_rel, H, nullptr, z_rel, rh_rel, nullptr, 0);

    if (have2) {
      // newh_rel partials (split-K S=2 into part2); reads m_rel, rh_rel
      MG(EPI_STORE, true, false, false, true, dim3(4, 64, 2), R_REL, H, H, H, KP_GRU / 32,
         m_rel, H, rh_rel, H, bt_nr_h, bt_nr_l, nullptr, nullptr,
         nullptr, nullptr, 0, nullptr, nullptr, nullptr, 0, nullptr, nullptr, nullptr, part2, 16);
      // GRU obj gates partials (S=8 into part = m_rel region; m_rel dead now)
      MG(EPI_STORE, true, false, false, true, dim3(8, 4, 8), N_OBJ, 2 * H, H, H, KP_GRU / 32,
         m_obj, H, h_obj, H, bt_go_h, bt_go_l, nullptr, nullptr,
         nullptr, nullptr, 0, nullptr, nullptr, nullptr, 0, nullptr, nullptr, nullptr, part, 4);
      epi_reduce<EPI_GATE><<<(N_OBJ * 2 * H + 255) / 256, blk, 0, stream>>>(
          8, N_OBJ, 2 * H, 2 * H, part, b_gru_obj, nullptr, 0, h_obj, H, nullptr, z_obj, rh_obj);
      // newh_obj partials (S=8 into part_no = rh_rel region; rh_rel dead now)
      MG(EPI_STORE, true, false, false, true, dim3(4, 4, 8), N_OBJ, H, H, H, KP_GRU / 32,
         m_obj, H, rh_obj, H, bt_no_h, bt_no_l, nullptr, nullptr,
         nullptr, nullptr, 0, nullptr, nullptr, nullptr, 0, nullptr, nullptr, nullptr, part_no, 4);
      // merged NEWH reduce (rel from part2 + obj from part_no); z_rel intact
      int nb1 = ((int)RH + 255) / 256;
      int nb2 = (N_OBJ * H + 255) / 256;
      epi_reduce2x<EPI_NEWH, EPI_NEWH><<<nb1 + nb2, blk, 0, stream>>>(
          nb1,
          2, R_REL, H, H, part2, b_gru_rel + 2 * H, h_rel, H, h_rel, z_rel, nullptr, nullptr,
          8, N_OBJ, H, H, part_no, b_gru_obj + 2 * H, h_obj, H, h_obj, z_obj, nullptr, nullptr);
    } else {
      // fallback: exact R12 sequence (direct NEWH for rel, split for obj)
      MG(EPI_NEWH, true, false, false, false, dim3(4, 64), R_REL, H, H, H, KP_GRU / 32,
         m_rel, H, rh_rel, H, bt_nr_h, bt_nr_l, nullptr, nullptr,
         b_gru_rel + 2 * H, h_rel, H, nullptr, nullptr, h_rel, H, z_rel, nullptr, nullptr, nullptr, 0);
      MG(EPI_STORE, true, false, false, true, dim3(8, 4, 8), N_OBJ, 2 * H, H, H, KP_GRU / 32,
         m_obj, H, h_obj, H, bt_go_h, bt_go_l, nullptr, nullptr,
         nullptr, nullptr, 0, nullptr, nullptr, nullptr, 0, nullptr, nullptr, nullptr, part, 4);
      epi_reduce<EPI_GATE><<<(N_OBJ * 2 * H + 255) / 256, blk, 0, stream>>>(
          8, N_OBJ, 2 * H, 2 * H, part, b_gru_obj, nullptr, 0, h_obj, H, nullptr, z_obj, rh_obj);
      MG(EPI_STORE, true, false, false, true, dim3(4, 4, 8), N_OBJ, H, H, H, KP_GRU / 32,
         m_obj, H, rh_obj, H, bt_no_h, bt_no_l, nullptr, nullptr,
         nullptr, nullptr, 0, nullptr, nullptr, nullptr, 0, nullptr, nullptr, nullptr, part, 4);
      epi_reduce<EPI_NEWH><<<(N_OBJ * H + 255) / 256, blk, 0, stream>>>(
          8, N_OBJ, H, H, part, b_gru_obj + 2 * H, h_obj, H, h_obj, H, z_obj, nullptr, nullptr);
    }
  }

  // classifier partial regions (scratch all dead now)
  float* part_crel = part;                               // 4 x 8192 x 128 = 4.19M
  float* part_cobj = part + (size_t)4 * R_REL * 128;     // 8 x 512 x 256  = 1.05M

  // rel_logits partials (N=51, padded bt to 128, split-K S=4)
  MG(EPI_STORE, false, false, false, true, dim3(1, 64, 4), R_REL, NRC, H, 0, KP_CLS / 32,
     h_rel, H, nullptr, 0, bt_cr_h, bt_cr_l, nullptr, nullptr,
     nullptr, nullptr, 0, nullptr, nullptr, nullptr, 0, nullptr, nullptr, nullptr, part_crel, 4);
  // obj_logits partials (N=151, padded bt to 256, split-K S=8)
  MG(EPI_STORE, false, false, false, true, dim3(2, 4, 8), N_OBJ, NOC, H, 0, KP_CLS / 32,
     h_obj, H, nullptr, 0, bt_co_h, bt_co_l, nullptr, nullptr,
     nullptr, nullptr, 0, nullptr, nullptr, nullptr, 0, nullptr, nullptr, nullptr, part_cobj, 2);
  // combined classifier reduce
  {
    int nb1 = (R_REL * 128 + 255) / 256;
    int nb2 = (N_OBJ * 256 + 255) / 256;
    epi_reduce2x<EPI_BIAS, EPI_BIAS><<<nb1 + nb2, blk, 0, stream>>>(
        nb1,
        4, R_REL, NRC, 128, part_crel, b_cls_rel, out_rel, NRC, nullptr, nullptr, nullptr, nullptr,
        8, N_OBJ, NOC, 256, part_cobj, b_cls_obj, out_logits, NOC, nullptr, nullptr, nullptr, nullptr);
  }

  // softmax -> NMS -> preds
  softmax_k<<<N_OBJ, 256, 0, stream>>>(out_logits, obj_probs2);
  nms_k<<<NOC - 1, 512, 0, stream>>>(obj_probs2, boxes, keepmask);
  pred_k<<<2, 256, 0, stream>>>(obj_probs2, keepmask, out_preds);
}

// Round 19
// 1229.019 us; speedup vs baseline: 1.1400x; 1.1257x over previous
//
#include <hip/hip_runtime.h>
#include <math.h>

#define OPI 64
#define RPI 1024
#define N_OBJ 512       // B*OPI
#define R_REL 8192      // B*RPI
#define OBJ_DIM 4096
#define H 512
#define NOC 151
#define NRC 51
#define T_ITERS 3
#define IOU_THRESH 0.3f

typedef unsigned short u16;
typedef unsigned int u32;
typedef unsigned long long u64;
typedef __attribute__((ext_vector_type(4))) float f32x4;
typedef __attribute__((ext_vector_type(8))) short bf16x8;
typedef __attribute__((ext_vector_type(2))) unsigned int u32x2;
typedef __attribute__((ext_vector_type(8))) short s16x8;

enum { EPI_STORE = 0, EPI_BIAS = 1, EPI_GATE = 3, EPI_NEWH = 4 };

__device__ inline u16 f2bf(float x) {
  u32 u = __float_as_uint(x);
  u32 r = (u + 0x7fffu + ((u >> 16) & 1u)) >> 16;
  return (u16)r;
}
__device__ inline float bf2f(u16 h) { return __uint_as_float(((u32)h) << 16); }
// HW packed fp32->bf16 (RTNE, matches f2bf): lo half = cvt(a), hi half = cvt(b)
__device__ inline u32 cvtpk(float a, float b) {
  u32 r;
  asm("v_cvt_pk_bf16_f32 %0, %1, %2" : "=v"(r) : "v"(a), "v"(b));
  return r;
}

// ---------------------------------------------------------------------------
// Merged weight prep (10 transpose/split jobs) + input softmax, ONE dispatch.
// ---------------------------------------------------------------------------
struct PJob {
  const float* W1; const float* W2; u16* oh; u16* ol;
  int ld1, K1, ld2, K2, coloff, ncols, N, Kpad, blk0, nkb;
};
struct PJobs { PJob j[10]; const float* smx_in; float* smx_out; int smx_blk0; };

__global__ __launch_bounds__(256) void prep_all(PJobs jobs) {
  __shared__ float tile[64][65];
  __shared__ float red[4];
  const int bid = blockIdx.x;
  const int t = threadIdx.x;

  if (bid >= jobs.smx_blk0) {           // ---- softmax rows
    int row = bid - jobs.smx_blk0;
    const float* X = jobs.smx_in;
    float* P = jobs.smx_out;
    float x = (t < NOC) ? X[row * NOC + t] : -3.4e38f;
    float m = x;
#pragma unroll
    for (int o = 32; o > 0; o >>= 1) m = fmaxf(m, __shfl_xor(m, o, 64));
    if ((t & 63) == 0) red[t >> 6] = m;
    __syncthreads();
    float mm = fmaxf(fmaxf(red[0], red[1]), fmaxf(red[2], red[3]));
    float e = (t < NOC) ? expf(x - mm) : 0.f;
    float s = e;
#pragma unroll
    for (int o = 32; o > 0; o >>= 1) s += __shfl_xor(s, o, 64);
    __syncthreads();
    if ((t & 63) == 0) red[t >> 6] = s;
    __syncthreads();
    float ss = red[0] + red[1] + red[2] + red[3];
    if (t < NOC) P[row * NOC + t] = e / ss;
    return;
  }

  int ji = 0;
#pragma unroll
  for (int i = 1; i < 10; ++i) if (bid >= jobs.j[i].blk0) ji = i;
  const PJob J = jobs.j[ji];
  const int local = bid - J.blk0;
  const int k0 = (local % J.nkb) * 64;
  const int n0 = (local / J.nkb) * 64;
  const int lane = t & 63;
  const int w = t >> 6;
#pragma unroll
  for (int p = 0; p < 16; ++p) {
    int kl = w * 16 + p;
    int k = k0 + kl;
    int n = n0 + lane;
    float v = 0.f;
    if (n < J.ncols) {
      if (k < J.K1) v = J.W1[(size_t)k * J.ld1 + J.coloff + n];
      else if (k - J.K1 < J.K2) v = J.W2[(size_t)(k - J.K1) * J.ld2 + J.coloff + n];
    }
    tile[kl][lane] = v;
  }
  __syncthreads();
#pragma unroll
  for (int p = 0; p < 16; ++p) {
    int nl = w * 16 + p;
    int n = n0 + nl;
    int k = k0 + lane;
    if (n < J.N && k < J.Kpad) {
      float v = tile[lane][nl];
      u16 h = f2bf(v);
      J.oh[(size_t)n * J.Kpad + k] = h;
      J.ol[(size_t)n * J.Kpad + k] = f2bf(v - bf2f(h));
    }
  }
}

// ---------------------------------------------------------------------------
// Split-bf16 MFMA GEMM (R18 core: deeper A-prefetch pipeline, dbuf LDS,
// cvtpk, setprio, XCD swizzle; 4 waves, 64x64 wave tile).
// ---------------------------------------------------------------------------
template<int EPI, bool DUAL, bool GATHER, bool PAIR, bool SPLIT>
__global__ __launch_bounds__(256, 2) void mgemm_k(
    int M, int N, int K1, int K2, int nkt,
    const float* __restrict__ A1, int lda1,
    const float* __restrict__ A2, int lda2,
    const u16* __restrict__ Bth, const u16* __restrict__ Btl,
    const u16* __restrict__ Bth2, const u16* __restrict__ Btl2,
    const float* __restrict__ bias,
    float* __restrict__ C, int ldc, float* __restrict__ C2,
    const int* __restrict__ ridx,
    const float* __restrict__ Hb, int ldh,
    const float* __restrict__ Zin,
    float* __restrict__ Zout, float* __restrict__ RHout,
    float* __restrict__ part, int ktchunk)
{
  __shared__ u16 lAh[2][128 * 32];
  __shared__ u16 lAl[2][128 * 32];
  __shared__ u16 lBh[2][128 * 32];
  __shared__ u16 lBl[2][128 * 32];
  const int t = threadIdx.x;
  const int lane = t & 63;
  const int wid = t >> 6;          // 0..3
  const int wm = wid >> 1;         // 0..1 (64-row half)
  const int wn = wid & 1;          // 0..1 (64-col half)

  // bijective XCD-aware swizzle over (x,y); all grids have nbx*nby % 8 == 0
  const int nbx = gridDim.x, nby = gridDim.y;
  const int nwg = nbx * nby;
  int orig = blockIdx.y * nbx + blockIdx.x;
  int lid = (orig & 7) * (nwg >> 3) + (orig >> 3);
  const int bx = lid % nbx;
  const int by = lid / nbx;

  const int m0 = by * 128;
  const int n0 = bx * 128;
  const int Kpad = nkt * 32;

  const float* A1p = A1; int ldap = lda1;
  const u16* Bhp = Bth; const u16* Blp = Btl;
  float* Cp = C;
  bool gath = GATHER;
  if (PAIR && blockIdx.z == 1) {
    A1p = A2; ldap = lda2; Bhp = Bth2; Blp = Btl2; Cp = C2; gath = false;
  }

  f32x4 acc[4][4];
#pragma unroll
  for (int m = 0; m < 4; ++m)
#pragma unroll
    for (int n = 0; n < 4; ++n) acc[m][n] = f32x4{0.f, 0.f, 0.f, 0.f};

  const int a_row = t >> 3;        // 0..31 (+i*32)
  const int a_kq  = t & 7;
  int g_si[4], g_oi[4];
  if (gath) {
#pragma unroll
    for (int i = 0; i < 4; ++i) {
      int gm = m0 + a_row + i * 32;
      g_si[i] = ridx[gm * 3 + 1];
      g_oi[i] = ridx[gm * 3 + 2];
    }
  }
  const int b_row  = t >> 2;       // 0..63 (+i*64)
  const int b_slot = t & 3;

  int ktb = 0, kte = nkt;
  if (SPLIT) {
    ktb = blockIdx.z * ktchunk;
    kte = min(nkt, ktb + ktchunk);
  }

  float4 rA[4];
  s16x8 rBh[2], rBl[2];

  auto loadA = [&](int kt) {
    const int gk = kt * 32 + a_kq * 4;
#pragma unroll
    for (int i = 0; i < 4; ++i) {
      const int gm = m0 + a_row + i * 32;
      if (gath) {
        float4 va = *(const float4*)&A1p[(size_t)g_si[i] * ldap + gk];
        float4 vb = *(const float4*)&A1p[(size_t)g_oi[i] * ldap + gk];
        rA[i] = make_float4(va.x + vb.x, va.y + vb.y, va.z + vb.z, va.w + vb.w);
      } else if (!DUAL) {
        rA[i] = *(const float4*)&A1p[(size_t)gm * ldap + gk];
      } else {
        if (gk + 3 < K1) {
          rA[i] = *(const float4*)&A1p[(size_t)gm * lda1 + gk];
        } else if (gk >= K1 && gk + 3 < K1 + K2 && (lda2 & 3) == 0) {
          rA[i] = *(const float4*)&A2[(size_t)gm * lda2 + (gk - K1)];
        } else {
          float xs[4];
#pragma unroll
          for (int e = 0; e < 4; ++e) {
            int gke = gk + e;
            float xv = 0.f;
            if (gke < K1) xv = A1p[(size_t)gm * lda1 + gke];
            else if (gke < K1 + K2) xv = A2[(size_t)gm * lda2 + (gke - K1)];
            xs[e] = xv;
          }
          rA[i] = make_float4(xs[0], xs[1], xs[2], xs[3]);
        }
      }
    }
  };
  auto loadB = [&](int kt) {
#pragma unroll
    for (int i = 0; i < 2; ++i) {
      const size_t goff = (size_t)(n0 + b_row + i * 64) * Kpad + kt * 32 + b_slot * 8;
      rBh[i] = *(const s16x8*)&Bhp[goff];
      rBl[i] = *(const s16x8*)&Blp[goff];
    }
  };
  auto stageA = [&](int buf) {
#pragma unroll
    for (int i = 0; i < 4; ++i) {
      const int row = a_row + i * 32;
      float x0 = rA[i].x, x1 = rA[i].y, x2 = rA[i].z, x3 = rA[i].w;
      u32 h01 = cvtpk(x0, x1);
      u32 h23 = cvtpk(x2, x3);
      float r0 = __uint_as_float(h01 << 16);
      float r1 = __uint_as_float(h01 & 0xffff0000u);
      float r2 = __uint_as_float(h23 << 16);
      float r3 = __uint_as_float(h23 & 0xffff0000u);
      u32 l01 = cvtpk(x0 - r0, x1 - r1);
      u32 l23 = cvtpk(x2 - r2, x3 - r3);
      const int base = row * 32 + (((a_kq >> 1) ^ ((row >> 1) & 3)) << 3) + (a_kq & 1) * 4;
      *reinterpret_cast<u32x2*>(&lAh[buf][base]) = u32x2{h01, h23};
      *reinterpret_cast<u32x2*>(&lAl[buf][base]) = u32x2{l01, l23};
    }
  };
  auto stageB = [&](int buf) {
#pragma unroll
    for (int i = 0; i < 2; ++i) {
      const int row = b_row + i * 64;
      const int base = row * 32 + ((b_slot ^ ((row >> 1) & 3)) << 3);
      *reinterpret_cast<s16x8*>(&lBh[buf][base]) = rBh[i];
      *reinterpret_cast<s16x8*>(&lBl[buf][base]) = rBl[i];
    }
  };

  const int fr = lane & 15;
  const int kg = lane >> 4;

  if (ktb < kte) {
    loadA(ktb);
    loadB(ktb);
    stageA(0);
    stageB(0);
    if (ktb + 1 < kte) loadA(ktb + 1);   // A prefetch runs one stage ahead
    __syncthreads();
    const int nk = kte - ktb;
    for (int kk = 0; kk < nk; ++kk) {
      const int cur = kk & 1;
      const bool more = (kk + 1 < nk);
      if (more) loadB(ktb + kk + 1);     // B 1-deep (L2-hot weights)
      bf16x8 ah[4], al[4], bh[4], bl[4];
#pragma unroll
      for (int m = 0; m < 4; ++m) {
        const int r = wm * 64 + m * 16 + fr;
        const int addr = r * 32 + ((kg ^ ((r >> 1) & 3)) << 3);
        ah[m] = *reinterpret_cast<const bf16x8*>(&lAh[cur][addr]);
        al[m] = *reinterpret_cast<const bf16x8*>(&lAl[cur][addr]);
      }
#pragma unroll
      for (int n = 0; n < 4; ++n) {
        const int r = wn * 64 + n * 16 + fr;
        const int addr = r * 32 + ((kg ^ ((r >> 1) & 3)) << 3);
        bh[n] = *reinterpret_cast<const bf16x8*>(&lBh[cur][addr]);
        bl[n] = *reinterpret_cast<const bf16x8*>(&lBl[cur][addr]);
      }
      if (more) stageA(cur ^ 1);          // consume rA (kt=kk+1) -> frees rA
      if (kk + 2 < nk) loadA(ktb + kk + 2);  // issue 2-ahead A load under MFMAs
      __builtin_amdgcn_s_setprio(1);
#pragma unroll
      for (int m = 0; m < 4; ++m)
#pragma unroll
        for (int n = 0; n < 4; ++n) {
          acc[m][n] = __builtin_amdgcn_mfma_f32_16x16x32_bf16(ah[m], bh[n], acc[m][n], 0, 0, 0);
          acc[m][n] = __builtin_amdgcn_mfma_f32_16x16x32_bf16(ah[m], bl[n], acc[m][n], 0, 0, 0);
          acc[m][n] = __builtin_amdgcn_mfma_f32_16x16x32_bf16(al[m], bh[n], acc[m][n], 0, 0, 0);
        }
      __builtin_amdgcn_s_setprio(0);
      if (more) stageB(cur ^ 1);
      __syncthreads();
    }
  }

  // ---- epilogue (C/D layout: col = lane&15, row = (lane>>4)*4 + j)
  const int col = lane & 15;
  const int rb = (lane >> 4) * 4;
  if (SPLIT) {
    const int Npad = gridDim.x * 128;
    float* pp = part + (size_t)blockIdx.z * M * Npad;
#pragma unroll
    for (int m = 0; m < 4; ++m)
#pragma unroll
      for (int n = 0; n < 4; ++n) {
        const int gn = n0 + wn * 64 + n * 16 + col;
#pragma unroll
        for (int j = 0; j < 4; ++j) {
          const int gm = m0 + wm * 64 + m * 16 + rb + j;
          pp[(size_t)gm * Npad + gn] = acc[m][n][j];
        }
      }
    return;
  }
#pragma unroll
  for (int m = 0; m < 4; ++m) {
#pragma unroll
    for (int n = 0; n < 4; ++n) {
      const int gn = n0 + wn * 64 + n * 16 + col;
      if (gn >= N) continue;
#pragma unroll
      for (int j = 0; j < 4; ++j) {
        const int gm = m0 + wm * 64 + m * 16 + rb + j;
        float v = acc[m][n][j];
        if (EPI == EPI_STORE) {
          Cp[(size_t)gm * ldc + gn] = v;
        } else if (EPI == EPI_BIAS) {
          Cp[(size_t)gm * ldc + gn] = v + bias[gn];
        } else if (EPI == EPI_GATE) {
          float g = 1.f / (1.f + expf(-(v + bias[gn])));
          int half = N >> 1;
          if (gn < half) Zout[(size_t)gm * half + gn] = g;
          else RHout[(size_t)gm * half + (gn - half)] = g * Hb[(size_t)gm * ldh + (gn - half)];
        } else if (EPI == EPI_NEWH) {
          float nv = tanhf(v + bias[gn]);
          float z = Zin[(size_t)gm * N + gn];
          float h = Hb[(size_t)gm * ldh + gn];
          Cp[(size_t)gm * ldc + gn] = (1.f - z) * h + z * nv;
        }
      }
    }
  }
}

// ---------------------------------------------------------------------------
// Split-K reduce + epilogue (single and dual-job).
// ---------------------------------------------------------------------------
template<int EPI>
__device__ inline void reduce_body(int blk, int S, int M, int N, int Npad,
    const float* __restrict__ part, const float* __restrict__ bias,
    float* __restrict__ C, int ldc,
    const float* __restrict__ Hb, int ldh,
    const float* __restrict__ Zin,
    float* __restrict__ Zout, float* __restrict__ RHout)
{
  int idx = blk * 256 + (int)threadIdx.x;
  if (idx >= M * Npad) return;
  int m = idx / Npad;
  int n = idx - m * Npad;
  if (n >= N) return;
  size_t stride = (size_t)M * Npad;
  float v = 0.f;
  for (int s = 0; s < S; ++s) v += part[s * stride + idx];
  if (EPI == EPI_BIAS) {
    C[(size_t)m * ldc + n] = v + bias[n];
  } else if (EPI == EPI_GATE) {
    float g = 1.f / (1.f + expf(-(v + bias[n])));
    int half = N >> 1;
    if (n < half) Zout[(size_t)m * half + n] = g;
    else RHout[(size_t)m * half + (n - half)] = g * Hb[(size_t)m * ldh + (n - half)];
  } else if (EPI == EPI_NEWH) {
    float nv = tanhf(v + bias[n]);
    float z = Zin[(size_t)m * N + n];
    float h = Hb[(size_t)m * ldh + n];
    C[(size_t)m * ldc + n] = (1.f - z) * h + z * nv;
  }
}

template<int EPI>
__global__ __launch_bounds__(256) void epi_reduce(
    int S, int M, int N, int Npad,
    const float* __restrict__ part, const float* __restrict__ bias,
    float* __restrict__ C, int ldc,
    const float* __restrict__ Hb, int ldh,
    const float* __restrict__ Zin,
    float* __restrict__ Zout, float* __restrict__ RHout)
{
  reduce_body<EPI>(blockIdx.x, S, M, N, Npad, part, bias, C, ldc, Hb, ldh, Zin, Zout, RHout);
}

template<int E1, int E2>
__global__ __launch_bounds__(256) void epi_reduce2x(
    int nblk1,
    int S1, int M1, int N1, int P1, const float* p1, const float* b1, float* C1, int l1,
    const float* Hb1, const float* Z1, float* Zo1, float* Rh1,
    int S2, int M2, int N2, int P2, const float* p2, const float* b2, float* C2, int l2,
    const float* Hb2, const float* Z2, float* Zo2, float* Rh2)
{
  if ((int)blockIdx.x < nblk1)
    reduce_body<E1>(blockIdx.x, S1, M1, N1, P1, p1, b1, C1, l1, Hb1, H, Z1, Zo1, Rh1);
  else
    reduce_body<E2>(blockIdx.x - nblk1, S2, M2, N2, P2, p2, b2, C2, l2, Hb2, H, Z2, Zo2, Rh2);
}

// row softmax over NOC=151 columns, one block per row
__global__ __launch_bounds__(256) void softmax_k(const float* __restrict__ X,
                                                 float* __restrict__ P)
{
  int row = blockIdx.x;
  int t = threadIdx.x;
  __shared__ float red[4];
  float x = (t < NOC) ? X[row * NOC + t] : -3.4e38f;
  float m = x;
#pragma unroll
  for (int o = 32; o > 0; o >>= 1) m = fmaxf(m, __shfl_xor(m, o, 64));
  if ((t & 63) == 0) red[t >> 6] = m;
  __syncthreads();
  float mm = fmaxf(fmaxf(red[0], red[1]), fmaxf(red[2], red[3]));
  float e = (t < NOC) ? expf(x - mm) : 0.f;
  float s = e;
#pragma unroll
  for (int o = 32; o > 0; o >>= 1) s += __shfl_xor(s, o, 64);
  __syncthreads();
  if ((t & 63) == 0) red[t >> 6] = s;
  __syncthreads();
  float ss = red[0] + red[1] + red[2] + red[3];
  if (t < NOC) P[row * NOC + t] = e / ss;
}

// ---------------------------------------------------------------------------
// m_obj gather v2: two-phase LDS-flag scan (ascending-r order preserved ->
// bit-identical sums). Phase 1: cooperative coalesced (s,o) load -> int flags
// in LDS. Phase 2: broadcast flag sweep; only matches (~32/block) pay the
// hm-row load. Replaces the 115-us latency-serial index scan.
// ---------------------------------------------------------------------------
__global__ __launch_bounds__(256) void m_obj_gather_k(const float* __restrict__ hm,
                                                      const int* __restrict__ ridx,
                                                      float* __restrict__ m_obj)
{
  __shared__ int flags[RPI];
  const int n = blockIdx.x;
  const int im = n >> 6;
  const int col = threadIdx.x;
  const int r0 = im * RPI;
#pragma unroll
  for (int j = 0; j < RPI / 256; ++j) {
    int r = (int)threadIdx.x + j * 256;
    int s = ridx[(size_t)(r0 + r) * 3 + 1];
    int o = ridx[(size_t)(r0 + r) * 3 + 2];
    flags[r] = (s == n) + (o == n);
  }
  __syncthreads();
  float acc0 = 0.f, acc1 = 0.f;
#pragma unroll 4
  for (int r = 0; r < RPI; ++r) {
    int c = flags[r];
    if (c) {
      float f = (float)c;
      acc0 = fmaf(f, hm[(size_t)(r0 + r) * H + col], acc0);
      acc1 = fmaf(f, hm[(size_t)(r0 + r) * H + col + 256], acc1);
    }
  }
  m_obj[n * H + col] = acc0;
  m_obj[n * H + col + 256] = acc1;
}

// ---------------------------------------------------------------------------
// Per-class NMS: stable bitonic sort + bitmask suppression.
// ---------------------------------------------------------------------------
__global__ __launch_bounds__(512) void nms_k(const float* __restrict__ probs2,
                                             const float* __restrict__ boxes,
                                             float* __restrict__ keepmask)
{
  int c = blockIdx.x + 1;
  int t = threadIdx.x;
  __shared__ float sc[512];
  __shared__ int   si[512];
  __shared__ float bx0[512], by0[512], bx1[512], by1[512], sar[512];
  __shared__ u64   msk[512][8];
  __shared__ u64   keepw_s[8];

  sc[t] = probs2[t * NOC + c];
  si[t] = t;
  __syncthreads();

  for (int k = 2; k <= 512; k <<= 1) {
    for (int j = k >> 1; j > 0; j >>= 1) {
      int p = t ^ j;
      if (p > t) {
        float s1 = sc[t], s2 = sc[p];
        int   i1 = si[t], i2 = si[p];
        bool tBefore = (s1 > s2) || (s1 == s2 && i1 < i2);
        bool up = ((t & k) == 0);
        if (up != tBefore) { sc[t] = s2; sc[p] = s1; si[t] = i2; si[p] = i1; }
      }
      __syncthreads();
    }
  }

  {
    const float* b = &boxes[(si[t] * NOC + c) * 4];
    float x0 = b[0], y0 = b[1], x1 = b[2], y1 = b[3];
    bx0[t] = x0; by0[t] = y0; bx1[t] = x1; by1[t] = y1;
    sar[t] = (x1 - x0) * (y1 - y0);
  }
  __syncthreads();

  {
    const float x0 = bx0[t], y0 = by0[t], x1 = bx1[t], y1 = by1[t], ar = sar[t];
#pragma unroll
    for (int w = 0; w < 8; ++w) {
      u64 bits = 0ull;
#pragma unroll 4
      for (int b = 0; b < 64; ++b) {
        const int j = w * 64 + b;
        float lx = fmaxf(x0, bx0[j]);
        float ly = fmaxf(y0, by0[j]);
        float rx = fminf(x1, bx1[j]);
        float ry = fminf(y1, by1[j]);
        float ww = fmaxf(rx - lx, 0.f);
        float hh = fmaxf(ry - ly, 0.f);
        float inter = ww * hh;
        float iou = inter / (ar + sar[j] - inter + 1e-9f);
        bits |= ((u64)((j > t) && (iou > IOU_THRESH))) << b;
      }
      msk[t][w] = bits;
    }
  }
  __syncthreads();

  if (t < 64) {
    const int w = t & 7;
    u64 keepw = ~0ull;
    u64 m = msk[0][w];
    for (int i = 0; i < 512; ++i) {
      u64 mn = (i + 1 < 512) ? msk[i + 1][w] : 0ull;
      u64 kw = __shfl(keepw, i >> 6, 64);
      if ((kw >> (i & 63)) & 1ull) keepw &= ~m;
      m = mn;
    }
    if (t < 8) keepw_s[t] = keepw;
  }
  __syncthreads();

  const u64 kw = keepw_s[t >> 6];
  keepmask[(c - 1) * N_OBJ + si[t]] = ((kw >> (t & 63)) & 1ull) ? 1.f : 0.f;
}

__global__ void pred_k(const float* __restrict__ probs2,
                       const float* __restrict__ keepmask,
                       float* __restrict__ out)
{
  int i = threadIdx.x + blockIdx.x * 256;
  if (i >= N_OBJ) return;
  float best = -1.f;
  int bc = 0;
  for (int c = 0; c < NOC - 1; ++c) {
    float v = keepmask[c * N_OBJ + i] * probs2[i * NOC + c + 1];
    if (v > best) { best = v; bc = c; }
  }
  out[i] = (float)(bc + 1);
}

extern "C" void kernel_launch(void* const* d_in, const int* in_sizes, int n_in,
                              void* d_out, int out_size, void* d_ws, size_t ws_size,
                              hipStream_t stream) {
  const float* obj_fmaps  = (const float*)d_in[1];
  const float* obj_logits = (const float*)d_in[2];
  const int*   rel_inds   = (const int*)d_in[3];
  const float* vr         = (const float*)d_in[4];
  const float* boxes      = (const float*)d_in[5];
  const float* W_obj_proj = (const float*)d_in[6];
  const float* b_obj_proj = (const float*)d_in[7];
  const float* W_rel_proj = (const float*)d_in[8];
  const float* b_rel_proj = (const float*)d_in[9];
  const float* W_emb      = (const float*)d_in[10];
  const float* W_msg_rel  = (const float*)d_in[11];
  const float* W_msg_obj  = (const float*)d_in[12];
  const float* W_gru_obj  = (const float*)d_in[13];
  const float* U_gru_obj  = (const float*)d_in[14];
  const float* b_gru_obj  = (const float*)d_in[15];
  const float* W_gru_rel  = (const float*)d_in[16];
  const float* U_gru_rel  = (const float*)d_in[17];
  const float* b_gru_rel  = (const float*)d_in[18];
  const float* W_cls_rel  = (const float*)d_in[19];
  const float* b_cls_rel  = (const float*)d_in[20];
  const float* W_cls_obj  = (const float*)d_in[21];
  const float* b_cls_obj  = (const float*)d_in[22];

  float* ws = (float*)d_ws;
  const size_t RH = (size_t)R_REL * H;     // 4,194,304
  const size_t NH = (size_t)N_OBJ * H;
  float* h_rel  = ws;
  float* m_rel  = h_rel  + RH;
  float* z_rel  = m_rel  + RH;   // aliased with hm
  float* rh_rel = z_rel  + RH;
  float* h_obj  = rh_rel + RH;
  float* m_obj  = h_obj  + NH;
  float* z_obj  = m_obj  + NH;
  float* rh_obj = z_obj  + NH;
  float* obj_probs  = rh_obj + NH;
  float* obj_probs2 = obj_probs  + (size_t)N_OBJ * NOC;
  float* keepmask   = obj_probs2 + (size_t)N_OBJ * NOC;
  float* hm   = z_rel;
  float* part = m_rel;           // m_rel region (4.19M floats) once m_rel dead
  float* part_no = rh_rel;       // rh_rel region (dead after newh_rel GEMM)
  float* fend = keepmask + (size_t)(NOC - 1) * N_OBJ;

  u16* bt = (u16*)fend;
  const int KP_HOBJ = 4256;
  const int KP_HREL = 4096;
  const int KP_MSG  = 512;
  const int KP_GRU  = 1024;
  const int KP_CLS  = 512;
  u16* p = bt;
  u16* bt_hobj_h = p; p += (size_t)H * KP_HOBJ;      u16* bt_hobj_l = p; p += (size_t)H * KP_HOBJ;
  u16* bt_hrel_h = p; p += (size_t)H * KP_HREL;      u16* bt_hrel_l = p; p += (size_t)H * KP_HREL;
  u16* bt_mrel_h = p; p += (size_t)H * KP_MSG;       u16* bt_mrel_l = p; p += (size_t)H * KP_MSG;
  u16* bt_hm_h   = p; p += (size_t)H * KP_MSG;       u16* bt_hm_l   = p; p += (size_t)H * KP_MSG;
  u16* bt_gr_h   = p; p += (size_t)2 * H * KP_GRU;   u16* bt_gr_l   = p; p += (size_t)2 * H * KP_GRU;
  u16* bt_nr_h   = p; p += (size_t)H * KP_GRU;       u16* bt_nr_l   = p; p += (size_t)H * KP_GRU;
  u16* bt_go_h   = p; p += (size_t)2 * H * KP_GRU;   u16* bt_go_l   = p; p += (size_t)2 * H * KP_GRU;
  u16* bt_no_h   = p; p += (size_t)H * KP_GRU;       u16* bt_no_l   = p; p += (size_t)H * KP_GRU;
  u16* bt_cr_h   = p; p += (size_t)128 * KP_CLS;     u16* bt_cr_l   = p; p += (size_t)128 * KP_CLS;
  u16* bt_co_h   = p; p += (size_t)256 * KP_CLS;     u16* bt_co_l   = p; p += (size_t)256 * KP_CLS;

  size_t used_b = (size_t)((char*)p - (char*)d_ws);
  used_b = (used_b + 15) & ~(size_t)15;
  float* part2 = (float*)((char*)d_ws + used_b);                 // 2*RH floats
  bool have2 = (used_b + 2 * RH * sizeof(float)) <= ws_size;

  float* out_logits = (float*)d_out;
  float* out_preds  = out_logits + (size_t)N_OBJ * NOC;
  float* out_rel    = out_preds + N_OBJ;

  dim3 blk(256);

  // ---- merged weight prep + input softmax (ONE dispatch)
  {
    PJobs pj;
    auto setj = [&](int i, const float* W1, int ld1, int K1, const float* W2, int ld2, int K2,
                    int coloff, int ncols, int N, int Kpad, u16* oh, u16* ol, int& blk0) {
      PJob& J = pj.j[i];
      J.W1 = W1; J.ld1 = ld1; J.K1 = K1; J.W2 = W2; J.ld2 = ld2; J.K2 = K2;
      J.coloff = coloff; J.ncols = ncols; J.N = N; J.Kpad = Kpad;
      J.oh = oh; J.ol = ol;
      J.nkb = (Kpad + 63) / 64;
      J.blk0 = blk0;
      blk0 += J.nkb * ((N + 63) / 64);
    };
    int b0 = 0;
    setj(0, W_obj_proj, H, OBJ_DIM, W_emb, H, NOC, 0, H, H, KP_HOBJ, bt_hobj_h, bt_hobj_l, b0);
    setj(1, W_rel_proj, H, OBJ_DIM, nullptr, 0, 0, 0, H, H, KP_HREL, bt_hrel_h, bt_hrel_l, b0);
    setj(2, W_msg_rel, H, H, nullptr, 0, 0, 0, H, H, KP_MSG, bt_mrel_h, bt_mrel_l, b0);
    setj(3, W_msg_obj, H, H, nullptr, 0, 0, 0, H, H, KP_MSG, bt_hm_h, bt_hm_l, b0);
    setj(4, W_gru_rel, 3 * H, H, U_gru_rel, 3 * H, H, 0, 2 * H, 2 * H, KP_GRU, bt_gr_h, bt_gr_l, b0);
    setj(5, W_gru_rel, 3 * H, H, U_gru_rel, 3 * H, H, 2 * H, H, H, KP_GRU, bt_nr_h, bt_nr_l, b0);
    setj(6, W_gru_obj, 3 * H, H, U_gru_obj, 3 * H, H, 0, 2 * H, 2 * H, KP_GRU, bt_go_h, bt_go_l, b0);
    setj(7, W_gru_obj, 3 * H, H, U_gru_obj, 3 * H, H, 2 * H, H, H, KP_GRU, bt_no_h, bt_no_l, b0);
    setj(8, W_cls_rel, NRC, H, nullptr, 0, 0, 0, NRC, 128, KP_CLS, bt_cr_h, bt_cr_l, b0);
    setj(9, W_cls_obj, NOC, H, nullptr, 0, 0, 0, NOC, 256, KP_CLS, bt_co_h, bt_co_l, b0);
    pj.smx_in = obj_logits;
    pj.smx_out = obj_probs;
    pj.smx_blk0 = b0;
    prep_all<<<b0 + N_OBJ, 256, 0, stream>>>(pj);
  }

#define MG(EPI, DUAL, GATH, PAIR, SPLIT, grid, M, N, K1, K2, nkt, A1, lda1, A2, lda2, \
           Bh, Bl, Bh2, Bl2, bias, C, ldc, C2, ridx, Hb, ldh, Zin, Zo, RHo, part, ktc) \
  mgemm_k<EPI, DUAL, GATH, PAIR, SPLIT><<<grid, blk, 0, stream>>>( \
      M, N, K1, K2, nkt, A1, lda1, A2, lda2, Bh, Bl, Bh2, Bl2, bias, C, ldc, C2, \
      ridx, Hb, ldh, Zin, Zo, RHo, part, ktc)

  // proj partial regions (disjoint within the 3*RH dead scratch)
  float* part_obj = part;                         // 8 x 512 x 512   = 2.10M
  float* part_rel = part + (size_t)8 * N_OBJ * H; // 2 x 8192 x 512  = 8.39M

  // h_obj partials (split-K S=8)
  MG(EPI_STORE, true, false, false, true, dim3(4, 4, 8), N_OBJ, H, OBJ_DIM, NOC, KP_HOBJ / 32,
     obj_fmaps, OBJ_DIM, obj_probs, NOC, bt_hobj_h, bt_hobj_l, nullptr, nullptr,
     nullptr, nullptr, 0, nullptr, nullptr, nullptr, 0, nullptr, nullptr, nullptr, part_obj, 17);
  // h_rel partials (split-K S=2)
  MG(EPI_STORE, false, false, false, true, dim3(4, 64, 2), R_REL, H, OBJ_DIM, 0, KP_HREL / 32,
     vr, OBJ_DIM, nullptr, 0, bt_hrel_h, bt_hrel_l, nullptr, nullptr,
     nullptr, nullptr, 0, nullptr, nullptr, nullptr, 0, nullptr, nullptr, nullptr, part_rel, 64);
  // combined reduce: h_obj then h_rel
  {
    int nb1 = (N_OBJ * H + 255) / 256;
    int nb2 = ((int)RH + 255) / 256;
    epi_reduce2x<EPI_BIAS, EPI_BIAS><<<nb1 + nb2, blk, 0, stream>>>(
        nb1,
        8, N_OBJ, H, H, part_obj, b_obj_proj, h_obj, H, nullptr, nullptr, nullptr, nullptr,
        2, R_REL, H, H, part_rel, b_rel_proj, h_rel, H, nullptr, nullptr, nullptr, nullptr);
  }

  for (int it = 0; it < T_ITERS; ++it) {
    // paired: z=0: m_rel = (h_obj[s]+h_obj[o]) @ W_msg_rel ; z=1: hm = h_rel @ W_msg_obj
    MG(EPI_STORE, false, true, true, false, dim3(4, 64, 2), R_REL, H, H, 0, KP_MSG / 32,
       h_obj, H, h_rel, H, bt_mrel_h, bt_mrel_l, bt_hm_h, bt_hm_l,
       nullptr, m_rel, H, hm, rel_inds, nullptr, 0, nullptr, nullptr, nullptr, nullptr, 0);
    m_obj_gather_k<<<N_OBJ, 256, 0, stream>>>(hm, rel_inds, m_obj);

    // GRU rel gates (512 blocks, direct EPI)
    MG(EPI_GATE, true, false, false, false, dim3(8, 64), R_REL, 2 * H, H, H, KP_GRU / 32,
       m_rel, H, h_rel, H, bt_gr_h, bt_gr_l, nullptr, nullptr,
       b_gru_rel, nullptr, 0, nullptr, nullptr, h_rel, H, nullptr, z_rel, rh_rel, nullptr, 0);

    if (have2) {
      // newh_rel partials (split-K S=2 into part2); reads m_rel, rh_rel
      MG(EPI_STORE, true, false, false, true, dim3(4, 64, 2), R_REL, H, H, H, KP_GRU / 32,
         m_rel, H, rh_rel, H, bt_nr_h, bt_nr_l, nullptr, nullptr,
         nullptr, nullptr, 0, nullptr, nullptr, nullptr, 0, nullptr, nullptr, nullptr, part2, 16);
      // GRU obj gates partials (S=8 into part = m_rel region; m_rel dead now)
      MG(EPI_STORE, true, false, false, true, dim3(8, 4, 8), N_OBJ, 2 * H, H, H, KP_GRU / 32,
         m_obj, H, h_obj, H, bt_go_h, bt_go_l, nullptr, nullptr,
         nullptr, nullptr, 0, nullptr, nullptr, nullptr, 0, nullptr, nullptr, nullptr, part, 4);
      epi_reduce<EPI_GATE><<<(N_OBJ * 2 * H + 255) / 256, blk, 0, stream>>>(
          8, N_OBJ, 2 * H, 2 * H, part, b_gru_obj, nullptr, 0, h_obj, H, nullptr, z_obj, rh_obj);
      // newh_obj partials (S=8 into part_no = rh_rel region; rh_rel dead now)
      MG(EPI_STORE, true, false, false, true, dim3(4, 4, 8), N_OBJ, H, H, H, KP_GRU / 32,
         m_obj, H, rh_obj, H, bt_no_h, bt_no_l, nullptr, nullptr,
         nullptr, nullptr, 0, nullptr, nullptr, nullptr, 0, nullptr, nullptr, nullptr, part_no, 4);
      // merged NEWH reduce (rel from part2 + obj from part_no); z_rel intact
      int nb1 = ((int)RH + 255) / 256;
      int nb2 = (N_OBJ * H + 255) / 256;
      epi_reduce2x<EPI_NEWH, EPI_NEWH><<<nb1 + nb2, blk, 0, stream>>>(
          nb1,
          2, R_REL, H, H, part2, b_gru_rel + 2 * H, h_rel, H, h_rel, z_rel, nullptr, nullptr,
          8, N_OBJ, H, H, part_no, b_gru_obj + 2 * H, h_obj, H, h_obj, z_obj, nullptr, nullptr);
    } else {
      // fallback: exact R12 sequence (direct NEWH for rel, split for obj)
      MG(EPI_NEWH, true, false, false, false, dim3(4, 64), R_REL, H, H, H, KP_GRU / 32,
         m_rel, H, rh_rel, H, bt_nr_h, bt_nr_l, nullptr, nullptr,
         b_gru_rel + 2 * H, h_rel, H, nullptr, nullptr, h_rel, H, z_rel, nullptr, nullptr, nullptr, 0);
      MG(EPI_STORE, true, false, false, true, dim3(8, 4, 8), N_OBJ, 2 * H, H, H, KP_GRU / 32,
         m_obj, H, h_obj, H, bt_go_h, bt_go_l, nullptr, nullptr,
         nullptr, nullptr, 0, nullptr, nullptr, nullptr, 0, nullptr, nullptr, nullptr, part, 4);
      epi_reduce<EPI_GATE><<<(N_OBJ * 2 * H + 255) / 256, blk, 0, stream>>>(
          8, N_OBJ, 2 * H, 2 * H, part, b_gru_obj, nullptr, 0, h_obj, H, nullptr, z_obj, rh_obj);
      MG(EPI_STORE, true, false, false, true, dim3(4, 4, 8), N_OBJ, H, H, H, KP_GRU / 32,
         m_obj, H, rh_obj, H, bt_no_h, bt_no_l, nullptr, nullptr,
         nullptr, nullptr, 0, nullptr, nullptr, nullptr, 0, nullptr, nullptr, nullptr, part, 4);
      epi_reduce<EPI_NEWH><<<(N_OBJ * H + 255) / 256, blk, 0, stream>>>(
          8, N_OBJ, H, H, part, b_gru_obj + 2 * H, h_obj, H, h_obj, H, z_obj, nullptr, nullptr);
    }
  }

  // classifier partial regions (scratch all dead now)
  float* part_crel = part;                               // 4 x 8192 x 128 = 4.19M
  float* part_cobj = part + (size_t)4 * R_REL * 128;     // 8 x 512 x 256  = 1.05M

  // rel_logits partials (N=51, padded bt to 128, split-K S=4)
  MG(EPI_STORE, false, false, false, true, dim3(1, 64, 4), R_REL, NRC, H, 0, KP_CLS / 32,
     h_rel, H, nullptr, 0, bt_cr_h, bt_cr_l, nullptr, nullptr,
     nullptr, nullptr, 0, nullptr, nullptr, nullptr, 0, nullptr, nullptr, nullptr, part_crel, 4);
  // obj_logits partials (N=151, padded bt to 256, split-K S=8)
  MG(EPI_STORE, false, false, false, true, dim3(2, 4, 8), N_OBJ, NOC, H, 0, KP_CLS / 32,
     h_obj, H, nullptr, 0, bt_co_h, bt_co_l, nullptr, nullptr,
     nullptr, nullptr, 0, nullptr, nullptr, nullptr, 0, nullptr, nullptr, nullptr, part_cobj, 2);
  // combined classifier reduce
  {
    int nb1 = (R_REL * 128 + 255) / 256;
    int nb2 = (N_OBJ * 256 + 255) / 256;
    epi_reduce2x<EPI_BIAS, EPI_BIAS><<<nb1 + nb2, blk, 0, stream>>>(
        nb1,
        4, R_REL, NRC, 128, part_crel, b_cls_rel, out_rel, NRC, nullptr, nullptr, nullptr, nullptr,
        8, N_OBJ, NOC, 256, part_cobj, b_cls_obj, out_logits, NOC, nullptr, nullptr, nullptr, nullptr);
  }

  // softmax -> NMS -> preds
  softmax_k<<<N_OBJ, 256, 0, stream>>>(out_logits, obj_probs2);
  nms_k<<<NOC - 1, 512, 0, stream>>>(obj_probs2, boxes, keepmask);
  pred_k<<<2, 256, 0, stream>>>(obj_probs2, keepmask, out_preds);
}